// Round 1
// baseline (3855.454 us; speedup 1.0000x reference)
//
#include <hip/hip_runtime.h>

static constexpr int IN_F = 128;
static constexpr int H_F  = 256;
static constexpr int NT   = 8;   // nodes per block in layer1

// ---- degree histogram: one thread per edge ----
__global__ void degree_kernel(const int* __restrict__ dst, float* __restrict__ deg, int E) {
    int e = blockIdx.x * blockDim.x + threadIdx.x;
    if (e < E) atomicAdd(&deg[dst[e]], 1.0f);
}

// ---- scatter-add of 128-float rows: one wave (64 lanes) per edge, 2 floats/lane ----
__global__ void scatter_add_128(const float* __restrict__ x,
                                const int* __restrict__ src,
                                const int* __restrict__ dst,
                                float* __restrict__ agg, int E) {
    int gid  = blockIdx.x * blockDim.x + threadIdx.x;
    int wave = gid >> 6;
    int lane = threadIdx.x & 63;
    if (wave >= E) return;
    int s = src[wave];
    int d = dst[wave];
    float2 v = ((const float2*)(x + (long long)s * IN_F))[lane];
    float* out = agg + (long long)d * IN_F + lane * 2;
    atomicAdd(out,     v.x);
    atomicAdd(out + 1, v.y);
}

// ---- scatter-add of 256-float rows: one wave per edge, 4 floats/lane ----
__global__ void scatter_add_256(const float* __restrict__ h,
                                const int* __restrict__ src,
                                const int* __restrict__ dst,
                                float* __restrict__ agg, int E) {
    int gid  = blockIdx.x * blockDim.x + threadIdx.x;
    int wave = gid >> 6;
    int lane = threadIdx.x & 63;
    if (wave >= E) return;
    int s = src[wave];
    int d = dst[wave];
    float4 v = ((const float4*)(h + (long long)s * H_F))[lane];
    float* out = agg + (long long)d * H_F + lane * 4;
    atomicAdd(out,     v.x);
    atomicAdd(out + 1, v.y);
    atomicAdd(out + 2, v.z);
    atomicAdd(out + 3, v.w);
}

// ---- fused layer 1: h = relu((agg1/deg) @ W1_l^T + b1 + x @ W1_r^T) ----
// Block = 256 threads (one thread per output feature j), NT nodes per block.
__global__ __launch_bounds__(256) void layer1_kernel(
        const float* __restrict__ x, const float* __restrict__ agg1,
        const float* __restrict__ deg,
        const float* __restrict__ W1l, const float* __restrict__ b1l,
        const float* __restrict__ W1r,
        float* __restrict__ h, int n) {
    __shared__ float sx[NT][IN_F];
    __shared__ float sa[NT][IN_F];
    int node0 = blockIdx.x * NT;
    int tid = threadIdx.x;

    for (int idx = tid; idx < NT * IN_F; idx += 256) {
        int nn = idx >> 7;
        int k  = idx & 127;
        int node = node0 + nn;
        float xv = 0.f, av = 0.f;
        if (node < n) {
            xv = x[(long long)node * IN_F + k];
            float dg = fmaxf(deg[node], 1.0f);
            av = agg1[(long long)node * IN_F + k] / dg;
        }
        sx[nn][k] = xv;
        sa[nn][k] = av;
    }
    __syncthreads();

    int j = tid;            // output feature 0..255
    float bj = b1l[j];
    float acc[NT];
#pragma unroll
    for (int nn = 0; nn < NT; nn++) acc[nn] = bj;

    for (int k = 0; k < IN_F; k++) {
        float wl = W1l[j * IN_F + k];
        float wr = W1r[j * IN_F + k];
#pragma unroll
        for (int nn = 0; nn < NT; nn++)
            acc[nn] += sa[nn][k] * wl + sx[nn][k] * wr;
    }

#pragma unroll
    for (int nn = 0; nn < NT; nn++) {
        int node = node0 + nn;
        if (node < n) h[(long long)node * H_F + j] = fmaxf(acc[nn], 0.0f);
    }
}

// ---- layer 2 epilogue: out[n] = (agg2[n]/deg)·W2l + b2 + h[n]·W2r ; one wave/node ----
__global__ void layer2_kernel(const float* __restrict__ h, const float* __restrict__ agg2,
                              const float* __restrict__ deg,
                              const float* __restrict__ W2l, const float* __restrict__ b2l,
                              const float* __restrict__ W2r,
                              float* __restrict__ out, int n) {
    int gid  = blockIdx.x * blockDim.x + threadIdx.x;
    int node = gid >> 6;
    int lane = threadIdx.x & 63;
    if (node >= n) return;
    float inv = 1.0f / fmaxf(deg[node], 1.0f);
    float4 hv  = ((const float4*)(h    + (long long)node * H_F))[lane];
    float4 av  = ((const float4*)(agg2 + (long long)node * H_F))[lane];
    float4 wlv = ((const float4*)W2l)[lane];
    float4 wrv = ((const float4*)W2r)[lane];
    float s = (av.x * wlv.x + av.y * wlv.y + av.z * wlv.z + av.w * wlv.w) * inv;
    s += hv.x * wrv.x + hv.y * wrv.y + hv.z * wrv.z + hv.w * wrv.w;
#pragma unroll
    for (int off = 32; off; off >>= 1) s += __shfl_down(s, off);
    if (lane == 0) out[node] = s + b2l[0];
}

extern "C" void kernel_launch(void* const* d_in, const int* in_sizes, int n_in,
                              void* d_out, int out_size, void* d_ws, size_t ws_size,
                              hipStream_t stream) {
    const float* x   = (const float*)d_in[0];
    const int*   ei  = (const int*)  d_in[1];
    const float* W1l = (const float*)d_in[2];
    const float* b1l = (const float*)d_in[3];
    const float* W1r = (const float*)d_in[4];
    const float* W2l = (const float*)d_in[5];
    const float* b2l = (const float*)d_in[6];
    const float* W2r = (const float*)d_in[7];
    float* out = (float*)d_out;

    int n = in_sizes[0] / IN_F;   // 50000
    int E = in_sizes[1] / 2;      // 800000
    const int* src = ei;
    const int* dst = ei + E;

    // workspace layout: [deg (n, padded)] [h (n*256)] [buf (n*256: agg1 then agg2)]
    float* deg = (float*)d_ws;
    float* h   = deg + (((size_t)n + 255) & ~(size_t)255);
    float* buf = h + (size_t)n * H_F;

    hipMemsetAsync(deg, 0, sizeof(float) * (size_t)n, stream);
    hipMemsetAsync(buf, 0, sizeof(float) * (size_t)n * IN_F, stream);

    degree_kernel<<<(E + 255) / 256, 256, 0, stream>>>(dst, deg, E);

    // one wave per edge
    scatter_add_128<<<(int)(((long long)E * 64 + 255) / 256), 256, 0, stream>>>(x, src, dst, buf, E);

    layer1_kernel<<<(n + NT - 1) / NT, 256, 0, stream>>>(x, buf, deg, W1l, b1l, W1r, h, n);

    hipMemsetAsync(buf, 0, sizeof(float) * (size_t)n * H_F, stream);

    scatter_add_256<<<(int)(((long long)E * 64 + 255) / 256), 256, 0, stream>>>(h, src, dst, buf, E);

    layer2_kernel<<<(int)(((long long)n * 64 + 255) / 256), 256, 0, stream>>>(
        h, buf, deg, W2l, b2l, W2r, out, n);
}

// Round 2
// 654.022 us; speedup vs baseline: 5.8950x; 5.8950x over previous
//
#include <hip/hip_runtime.h>

static constexpr int IN_F = 128;
static constexpr int H_F  = 256;
static constexpr int NT   = 8;   // nodes per block in layer1

// ---- degree histogram (int) ----
__global__ void degree_kernel(const int* __restrict__ dst, int* __restrict__ degi, int E) {
    int e = blockIdx.x * blockDim.x + threadIdx.x;
    if (e < E) atomicAdd(&degi[dst[e]], 1);
}

// ---- single-block exclusive scan over degi -> rowptr, cursor ----
__global__ __launch_bounds__(1024) void scan_kernel(const int* __restrict__ degi,
                                                    int* __restrict__ rowptr,
                                                    int* __restrict__ cursor,
                                                    int n, int Etot) {
    __shared__ int wsum[16];
    __shared__ int s_running;
    int tid  = threadIdx.x;
    int lane = tid & 63;
    int wid  = tid >> 6;
    if (tid == 0) s_running = 0;
    __syncthreads();
    for (int base = 0; base < n; base += 1024) {
        int i = base + tid;
        int v = (i < n) ? degi[i] : 0;
        int val = v;
        // wave-inclusive scan
#pragma unroll
        for (int off = 1; off < 64; off <<= 1) {
            int t = __shfl_up(val, off);
            if (lane >= off) val += t;
        }
        if (lane == 63) wsum[wid] = val;
        __syncthreads();
        if (wid == 0 && lane < 16) {
            int s = wsum[lane];
#pragma unroll
            for (int off = 1; off < 16; off <<= 1) {
                int t = __shfl_up(s, off);
                if (lane >= off) s += t;
            }
            wsum[lane] = s;
        }
        __syncthreads();
        int woff = (wid > 0) ? wsum[wid - 1] : 0;
        int incl = val + woff;
        int run  = s_running;
        if (i < n) {
            int ex = run + incl - v;
            rowptr[i] = ex;
            cursor[i] = ex;
        }
        __syncthreads();
        if (tid == 1023) s_running = run + wsum[15];
        __syncthreads();
    }
    if (tid == 0) rowptr[n] = Etot;
}

// ---- CSR fill ----
__global__ void fill_kernel(const int* __restrict__ src, const int* __restrict__ dst,
                            int* __restrict__ cursor, int* __restrict__ col, int E) {
    int e = blockIdx.x * blockDim.x + threadIdx.x;
    if (e < E) {
        int pos = atomicAdd(&cursor[dst[e]], 1);
        col[pos] = src[e];
    }
}

// ---- agg1: mean of x rows over CSR neighbors; one wave per node, float2/lane ----
__global__ void agg1_kernel(const float* __restrict__ x,
                            const int* __restrict__ rowptr, const int* __restrict__ col,
                            float* __restrict__ agg1, int n) {
    int gid  = blockIdx.x * blockDim.x + threadIdx.x;
    int node = gid >> 6;
    int lane = threadIdx.x & 63;
    if (node >= n) return;
    int beg = rowptr[node], end = rowptr[node + 1];
    float ax = 0.f, ay = 0.f;
    int j = beg;
    for (; j + 1 < end; j += 2) {
        int s0 = col[j], s1 = col[j + 1];
        float2 v0 = ((const float2*)(x + (size_t)s0 * IN_F))[lane];
        float2 v1 = ((const float2*)(x + (size_t)s1 * IN_F))[lane];
        ax += v0.x + v1.x;
        ay += v0.y + v1.y;
    }
    if (j < end) {
        int s0 = col[j];
        float2 v0 = ((const float2*)(x + (size_t)s0 * IN_F))[lane];
        ax += v0.x;
        ay += v0.y;
    }
    float inv = 1.0f / fmaxf((float)(end - beg), 1.0f);
    ((float2*)(agg1 + (size_t)node * IN_F))[lane] = make_float2(ax * inv, ay * inv);
}

// ---- fused layer1 + layer2 projections:
//   h = relu(agg1 @ W1l^T + b1 + x @ W1r^T)   (kept in registers, never stored)
//   p = h . W2l ; q = h . W2r                 (block reduction, 2 scalars per node)
__global__ __launch_bounds__(256) void layer1_kernel(
        const float* __restrict__ x, const float* __restrict__ agg1,
        const float* __restrict__ W1l, const float* __restrict__ b1l,
        const float* __restrict__ W1r,
        const float* __restrict__ W2l, const float* __restrict__ W2r,
        float* __restrict__ p, float* __restrict__ q, int n) {
    __shared__ float sx[NT][IN_F];
    __shared__ float sa[NT][IN_F];
    __shared__ float redp[NT][4];
    __shared__ float redq[NT][4];
    int node0 = blockIdx.x * NT;
    int tid = threadIdx.x;
    int lane = tid & 63;
    int wid  = tid >> 6;

    for (int idx = tid; idx < NT * IN_F; idx += 256) {
        int nn = idx >> 7;
        int k  = idx & 127;
        int node = node0 + nn;
        float xv = 0.f, av = 0.f;
        if (node < n) {
            xv = x[(size_t)node * IN_F + k];
            av = agg1[(size_t)node * IN_F + k];   // already mean
        }
        sx[nn][k] = xv;
        sa[nn][k] = av;
    }
    __syncthreads();

    int j = tid;  // output feature 0..255
    float bj = b1l[j];
    float acc[NT];
#pragma unroll
    for (int nn = 0; nn < NT; nn++) acc[nn] = bj;

    for (int k = 0; k < IN_F; k++) {
        float wl = W1l[j * IN_F + k];
        float wr = W1r[j * IN_F + k];
#pragma unroll
        for (int nn = 0; nn < NT; nn++)
            acc[nn] += sa[nn][k] * wl + sx[nn][k] * wr;
    }

    float w2l = W2l[j];
    float w2r = W2r[j];
#pragma unroll
    for (int nn = 0; nn < NT; nn++) {
        float hv = fmaxf(acc[nn], 0.0f);
        float u = hv * w2l;
        float v = hv * w2r;
#pragma unroll
        for (int off = 32; off; off >>= 1) {
            u += __shfl_down(u, off);
            v += __shfl_down(v, off);
        }
        if (lane == 0) { redp[nn][wid] = u; redq[nn][wid] = v; }
    }
    __syncthreads();
    if (tid < NT) {
        int node = node0 + tid;
        if (node < n) {
            p[node] = redp[tid][0] + redp[tid][1] + redp[tid][2] + redp[tid][3];
            q[node] = redq[tid][0] + redq[tid][1] + redq[tid][2] + redq[tid][3];
        }
    }
}

// ---- final: out[n] = mean(p[neighbors]) + b2 + q[n]; one wave per node ----
__global__ void out_kernel(const float* __restrict__ p, const float* __restrict__ q,
                           const int* __restrict__ rowptr, const int* __restrict__ col,
                           const float* __restrict__ b2l,
                           float* __restrict__ out, int n) {
    int gid  = blockIdx.x * blockDim.x + threadIdx.x;
    int node = gid >> 6;
    int lane = threadIdx.x & 63;
    if (node >= n) return;
    int beg = rowptr[node], end = rowptr[node + 1];
    float s = 0.f;
    for (int j = beg + lane; j < end; j += 64) s += p[col[j]];
#pragma unroll
    for (int off = 32; off; off >>= 1) s += __shfl_down(s, off);
    if (lane == 0) {
        float inv = 1.0f / fmaxf((float)(end - beg), 1.0f);
        out[node] = s * inv + b2l[0] + q[node];
    }
}

extern "C" void kernel_launch(void* const* d_in, const int* in_sizes, int n_in,
                              void* d_out, int out_size, void* d_ws, size_t ws_size,
                              hipStream_t stream) {
    const float* x   = (const float*)d_in[0];
    const int*   ei  = (const int*)  d_in[1];
    const float* W1l = (const float*)d_in[2];
    const float* b1l = (const float*)d_in[3];
    const float* W1r = (const float*)d_in[4];
    const float* W2l = (const float*)d_in[5];
    const float* b2l = (const float*)d_in[6];
    const float* W2r = (const float*)d_in[7];
    float* out = (float*)d_out;

    int n = in_sizes[0] / IN_F;   // 50000
    int E = in_sizes[1] / 2;      // 800000
    const int* src = ei;
    const int* dst = ei + E;

    size_t n_pad = ((size_t)n + 256) & ~(size_t)255;  // >= n+1, 256-aligned

    int* degi   = (int*)d_ws;            // n
    int* rowptr = degi + n_pad;          // n+1
    int* cursor = rowptr + n_pad;        // n
    int* col    = cursor + n_pad;        // E
    float* agg1 = (float*)(col + (((size_t)E + 255) & ~(size_t)255)); // n*128
    float* p    = agg1 + (size_t)n * IN_F;
    float* q    = p + n_pad;

    hipMemsetAsync(degi, 0, sizeof(int) * (size_t)n, stream);

    degree_kernel<<<(E + 255) / 256, 256, 0, stream>>>(dst, degi, E);
    scan_kernel<<<1, 1024, 0, stream>>>(degi, rowptr, cursor, n, E);
    fill_kernel<<<(E + 255) / 256, 256, 0, stream>>>(src, dst, cursor, col, E);

    agg1_kernel<<<(int)(((size_t)n * 64 + 255) / 256), 256, 0, stream>>>(x, rowptr, col, agg1, n);

    layer1_kernel<<<(n + NT - 1) / NT, 256, 0, stream>>>(
        x, agg1, W1l, b1l, W1r, W2l, W2r, p, q, n);

    out_kernel<<<(int)(((size_t)n * 64 + 255) / 256), 256, 0, stream>>>(
        p, q, rowptr, col, b2l, out, n);
}

// Round 3
// 350.033 us; speedup vs baseline: 11.0145x; 1.8685x over previous
//
#include <hip/hip_runtime.h>

static constexpr int IN_F = 128;

// ===================== CSR construction =====================

__global__ void degree_kernel(const int* __restrict__ dst, int* __restrict__ degi, int E) {
    int e = blockIdx.x * blockDim.x + threadIdx.x;
    if (e < E) atomicAdd(&degi[dst[e]], 1);
}

// S1: per-block (256 elems) sum of degi -> bsum[b]
__global__ __launch_bounds__(256) void scan_part(const int* __restrict__ degi,
                                                 int* __restrict__ bsum, int n) {
    __shared__ int ws[4];
    int i = blockIdx.x * 256 + threadIdx.x;
    int lane = threadIdx.x & 63, wid = threadIdx.x >> 6;
    int v = (i < n) ? degi[i] : 0;
#pragma unroll
    for (int off = 32; off; off >>= 1) v += __shfl_down(v, off);
    if (lane == 0) ws[wid] = v;
    __syncthreads();
    if (threadIdx.x == 0) bsum[blockIdx.x] = ws[0] + ws[1] + ws[2] + ws[3];
}

// S2: single block, exclusive scan of bsum[0..NB) -> boff; also rowptr[n]=E
__global__ __launch_bounds__(1024) void scan_offsets(const int* __restrict__ bsum,
                                                     int* __restrict__ boff, int NB,
                                                     int* __restrict__ rowptr, int n, int E) {
    __shared__ int ws[16];
    int t = threadIdx.x;
    int lane = t & 63, wid = t >> 6;
    int v = (t < NB) ? bsum[t] : 0;
    int val = v;
#pragma unroll
    for (int off = 1; off < 64; off <<= 1) {
        int tt = __shfl_up(val, off);
        if (lane >= off) val += tt;
    }
    if (lane == 63) ws[wid] = val;
    __syncthreads();
    if (wid == 0 && lane < 16) {
        int s = ws[lane];
#pragma unroll
        for (int off = 1; off < 16; off <<= 1) {
            int tt = __shfl_up(s, off);
            if (lane >= off) s += tt;
        }
        ws[lane] = s;
    }
    __syncthreads();
    int woff = (wid > 0) ? ws[wid - 1] : 0;
    if (t < NB) boff[t] = woff + val - v;   // exclusive
    if (t == 0) rowptr[n] = E;
}

// S3: per-block exclusive scan of degi + boff[b] -> rowptr, cursor
__global__ __launch_bounds__(256) void scan_apply(const int* __restrict__ degi,
                                                  const int* __restrict__ boff,
                                                  int* __restrict__ rowptr,
                                                  int* __restrict__ cursor, int n) {
    __shared__ int ws[4];
    int i = blockIdx.x * 256 + threadIdx.x;
    int lane = threadIdx.x & 63, wid = threadIdx.x >> 6;
    int v = (i < n) ? degi[i] : 0;
    int val = v;
#pragma unroll
    for (int off = 1; off < 64; off <<= 1) {
        int t = __shfl_up(val, off);
        if (lane >= off) val += t;
    }
    if (lane == 63) ws[wid] = val;
    __syncthreads();
    int woff = boff[blockIdx.x];
    for (int w = 0; w < wid; w++) woff += ws[w];
    if (i < n) {
        int ex = woff + val - v;
        rowptr[i] = ex;
        cursor[i] = ex;
    }
}

__global__ void fill_kernel(const int* __restrict__ src, const int* __restrict__ dst,
                            int* __restrict__ cursor, int* __restrict__ col, int E) {
    int e = blockIdx.x * blockDim.x + threadIdx.x;
    if (e < E) {
        int pos = atomicAdd(&cursor[dst[e]], 1);
        col[pos] = src[e];
    }
}

// ===================== agg1: mean of x rows over CSR =====================
__global__ void agg1_kernel(const float* __restrict__ x,
                            const int* __restrict__ rowptr, const int* __restrict__ col,
                            float* __restrict__ agg1, int n) {
    int gid  = blockIdx.x * blockDim.x + threadIdx.x;
    int node = gid >> 6;
    int lane = threadIdx.x & 63;
    if (node >= n) return;
    int beg = rowptr[node], end = rowptr[node + 1];
    float ax = 0.f, ay = 0.f;
    int j = beg;
    for (; j + 1 < end; j += 2) {
        int s0 = col[j], s1 = col[j + 1];
        float2 v0 = ((const float2*)(x + (size_t)s0 * IN_F))[lane];
        float2 v1 = ((const float2*)(x + (size_t)s1 * IN_F))[lane];
        ax += v0.x + v1.x;
        ay += v0.y + v1.y;
    }
    if (j < end) {
        float2 v0 = ((const float2*)(x + (size_t)col[j] * IN_F))[lane];
        ax += v0.x;
        ay += v0.y;
    }
    float inv = 1.0f / fmaxf((float)(end - beg), 1.0f);
    ((float2*)(agg1 + (size_t)node * IN_F))[lane] = make_float2(ax * inv, ay * inv);
}

// ===================== fused layer1 + layer2 projections =====================
// C[64 nodes x 256 feats] = [agg1|x] @ [W1l|W1r]^T + b1, relu, then
// p = h.W2l, q = h.W2r reduced per node (h never stored).
// Thread tile: 16 nodes x 4 feats. wave ng owns nodes node0+ng*16..+15.
static constexpr int SA_STRIDE = 68;    // 64 nodes + 4 pad
static constexpr int SB_STRIDE = 260;   // 256 feats + 4 pad

__global__ __launch_bounds__(256) void layer1_kernel(
        const float* __restrict__ x, const float* __restrict__ agg1,
        const float* __restrict__ W1l, const float* __restrict__ b1l,
        const float* __restrict__ W1r,
        const float* __restrict__ W2l, const float* __restrict__ W2r,
        float* __restrict__ p, float* __restrict__ q, int n) {
    __shared__ float sA[32 * SA_STRIDE];   // [k][node]
    __shared__ float sB[32 * SB_STRIDE];   // [k][feat]

    int tid  = threadIdx.x;
    int lane = tid & 63;
    int ng   = tid >> 6;          // wave id = node group
    int jq   = lane;              // feature quad 0..63 -> feats jq*4..+3
    int node0 = blockIdx.x * 64;
    int m0 = ng * 16;

    float4 bias = ((const float4*)b1l)[jq];
    float4 acc[16];
#pragma unroll
    for (int i = 0; i < 16; i++) acc[i] = bias;

    int kk = tid & 7;        // float4 index within 32-k chunk
    int rowi = tid >> 3;     // 0..31

    for (int kc = 0; kc < 8; kc++) {
        int k0 = kc * 32;
        const float* Asrc = (k0 < 128) ? (agg1 + k0) : (x + (k0 - 128));
        const float* Bsrc = (k0 < 128) ? (W1l + k0) : (W1r + (k0 - 128));
        // stage A: 64 nodes x 32 k
#pragma unroll
        for (int r = 0; r < 2; r++) {
            int nd = rowi + r * 32;
            int g  = node0 + nd;
            float4 v = make_float4(0.f, 0.f, 0.f, 0.f);
            if (g < n) v = *(const float4*)(Asrc + (size_t)g * IN_F + kk * 4);
            sA[(kk * 4 + 0) * SA_STRIDE + nd] = v.x;
            sA[(kk * 4 + 1) * SA_STRIDE + nd] = v.y;
            sA[(kk * 4 + 2) * SA_STRIDE + nd] = v.z;
            sA[(kk * 4 + 3) * SA_STRIDE + nd] = v.w;
        }
        // stage B: 256 feats x 32 k
#pragma unroll
        for (int r = 0; r < 8; r++) {
            int j = rowi + r * 32;
            float4 v = *(const float4*)(Bsrc + (size_t)j * IN_F + kk * 4);
            sB[(kk * 4 + 0) * SB_STRIDE + j] = v.x;
            sB[(kk * 4 + 1) * SB_STRIDE + j] = v.y;
            sB[(kk * 4 + 2) * SB_STRIDE + j] = v.z;
            sB[(kk * 4 + 3) * SB_STRIDE + j] = v.w;
        }
        __syncthreads();

#pragma unroll 2
        for (int k = 0; k < 32; k++) {
            float4 b4 = *(const float4*)&sB[k * SB_STRIDE + jq * 4];
            const float* ar = &sA[k * SA_STRIDE + m0];
            float4 a0 = *(const float4*)(ar + 0);
            float4 a1 = *(const float4*)(ar + 4);
            float4 a2 = *(const float4*)(ar + 8);
            float4 a3 = *(const float4*)(ar + 12);
            float av[16] = {a0.x,a0.y,a0.z,a0.w, a1.x,a1.y,a1.z,a1.w,
                            a2.x,a2.y,a2.z,a2.w, a3.x,a3.y,a3.z,a3.w};
#pragma unroll
            for (int i = 0; i < 16; i++) {
                acc[i].x += av[i] * b4.x;
                acc[i].y += av[i] * b4.y;
                acc[i].z += av[i] * b4.z;
                acc[i].w += av[i] * b4.w;
            }
        }
        __syncthreads();
    }

    // epilogue: relu, project to p/q scalars, wave-reduce over 64 lanes (all feats)
    float4 w2l = ((const float4*)W2l)[jq];
    float4 w2r = ((const float4*)W2r)[jq];
#pragma unroll
    for (int i = 0; i < 16; i++) {
        float hx = fmaxf(acc[i].x, 0.f), hy = fmaxf(acc[i].y, 0.f);
        float hz = fmaxf(acc[i].z, 0.f), hw = fmaxf(acc[i].w, 0.f);
        float u = hx * w2l.x + hy * w2l.y + hz * w2l.z + hw * w2l.w;
        float v = hx * w2r.x + hy * w2r.y + hz * w2r.z + hw * w2r.w;
#pragma unroll
        for (int off = 32; off; off >>= 1) {
            u += __shfl_down(u, off);
            v += __shfl_down(v, off);
        }
        if (lane == 0) {
            int node = node0 + m0 + i;
            if (node < n) { p[node] = u; q[node] = v; }
        }
    }
}

// ===================== final: out = mean(p[neigh]) + b2 + q =====================
__global__ void out_kernel(const float* __restrict__ p, const float* __restrict__ q,
                           const int* __restrict__ rowptr, const int* __restrict__ col,
                           const float* __restrict__ b2l,
                           float* __restrict__ out, int n) {
    int gid  = blockIdx.x * blockDim.x + threadIdx.x;
    int node = gid >> 6;
    int lane = threadIdx.x & 63;
    if (node >= n) return;
    int beg = rowptr[node], end = rowptr[node + 1];
    float s = 0.f;
    for (int j = beg + lane; j < end; j += 64) s += p[col[j]];
#pragma unroll
    for (int off = 32; off; off >>= 1) s += __shfl_down(s, off);
    if (lane == 0) {
        float inv = 1.0f / fmaxf((float)(end - beg), 1.0f);
        out[node] = s * inv + b2l[0] + q[node];
    }
}

extern "C" void kernel_launch(void* const* d_in, const int* in_sizes, int n_in,
                              void* d_out, int out_size, void* d_ws, size_t ws_size,
                              hipStream_t stream) {
    const float* x   = (const float*)d_in[0];
    const int*   ei  = (const int*)  d_in[1];
    const float* W1l = (const float*)d_in[2];
    const float* b1l = (const float*)d_in[3];
    const float* W1r = (const float*)d_in[4];
    const float* W2l = (const float*)d_in[5];
    const float* b2l = (const float*)d_in[6];
    const float* W2r = (const float*)d_in[7];
    float* out = (float*)d_out;

    int n = in_sizes[0] / IN_F;   // 50000
    int E = in_sizes[1] / 2;      // 800000
    const int* src = ei;
    const int* dst = ei + E;

    size_t n_pad = ((size_t)n + 256) & ~(size_t)255;
    int NB = (n + 255) / 256;

    int* degi   = (int*)d_ws;            // n
    int* rowptr = degi + n_pad;          // n+1
    int* cursor = rowptr + n_pad;        // n
    int* bsum   = cursor + n_pad;        // NB (<=1024)
    int* boff   = bsum + 1024;           // NB
    int* col    = boff + 1024;           // E
    float* agg1 = (float*)(col + (((size_t)E + 255) & ~(size_t)255)); // n*128
    float* p    = agg1 + (size_t)n * IN_F;
    float* q    = p + n_pad;

    hipMemsetAsync(degi, 0, sizeof(int) * (size_t)n, stream);

    degree_kernel<<<(E + 255) / 256, 256, 0, stream>>>(dst, degi, E);
    scan_part<<<NB, 256, 0, stream>>>(degi, bsum, n);
    scan_offsets<<<1, 1024, 0, stream>>>(bsum, boff, NB, rowptr, n, E);
    scan_apply<<<NB, 256, 0, stream>>>(degi, boff, rowptr, cursor, n);
    fill_kernel<<<(E + 255) / 256, 256, 0, stream>>>(src, dst, cursor, col, E);

    agg1_kernel<<<(int)(((size_t)n * 64 + 255) / 256), 256, 0, stream>>>(x, rowptr, col, agg1, n);

    layer1_kernel<<<(n + 63) / 64, 256, 0, stream>>>(
        x, agg1, W1l, b1l, W1r, W2l, W2r, p, q, n);

    out_kernel<<<(int)(((size_t)n * 64 + 255) / 256), 256, 0, stream>>>(
        p, q, rowptr, col, b2l, out, n);
}

// Round 4
// 271.004 us; speedup vs baseline: 14.2266x; 1.2916x over previous
//
#include <hip/hip_runtime.h>

static constexpr int IN_F = 128;

typedef __attribute__((ext_vector_type(8))) short bf16x8;
typedef __attribute__((ext_vector_type(8))) unsigned short u16x8;
typedef __attribute__((ext_vector_type(4))) float f32x4;

__device__ inline unsigned short f2bf(float f) {   // RNE f32->bf16
    unsigned u = __float_as_uint(f);
    u += 0x7FFF + ((u >> 16) & 1);
    return (unsigned short)(u >> 16);
}
__device__ inline float bf2f(unsigned short h) {
    return __uint_as_float(((unsigned)h) << 16);
}

// ===================== CSR construction =====================

__global__ void degree_kernel(const int* __restrict__ dst, int* __restrict__ degi, int E) {
    int e = blockIdx.x * blockDim.x + threadIdx.x;
    if (e < E) atomicAdd(&degi[dst[e]], 1);
}

__global__ __launch_bounds__(256) void scan_part(const int* __restrict__ degi,
                                                 int* __restrict__ bsum, int n) {
    __shared__ int ws[4];
    int i = blockIdx.x * 256 + threadIdx.x;
    int lane = threadIdx.x & 63, wid = threadIdx.x >> 6;
    int v = (i < n) ? degi[i] : 0;
#pragma unroll
    for (int off = 32; off; off >>= 1) v += __shfl_down(v, off);
    if (lane == 0) ws[wid] = v;
    __syncthreads();
    if (threadIdx.x == 0) bsum[blockIdx.x] = ws[0] + ws[1] + ws[2] + ws[3];
}

__global__ __launch_bounds__(1024) void scan_offsets(const int* __restrict__ bsum,
                                                     int* __restrict__ boff, int NB,
                                                     int* __restrict__ rowptr, int n, int E) {
    __shared__ int ws[16];
    int t = threadIdx.x;
    int lane = t & 63, wid = t >> 6;
    int v = (t < NB) ? bsum[t] : 0;
    int val = v;
#pragma unroll
    for (int off = 1; off < 64; off <<= 1) {
        int tt = __shfl_up(val, off);
        if (lane >= off) val += tt;
    }
    if (lane == 63) ws[wid] = val;
    __syncthreads();
    if (wid == 0 && lane < 16) {
        int s = ws[lane];
#pragma unroll
        for (int off = 1; off < 16; off <<= 1) {
            int tt = __shfl_up(s, off);
            if (lane >= off) s += tt;
        }
        ws[lane] = s;
    }
    __syncthreads();
    int woff = (wid > 0) ? ws[wid - 1] : 0;
    if (t < NB) boff[t] = woff + val - v;
    if (t == 0) rowptr[n] = E;
}

__global__ __launch_bounds__(256) void scan_apply(const int* __restrict__ degi,
                                                  const int* __restrict__ boff,
                                                  int* __restrict__ rowptr,
                                                  int* __restrict__ cursor, int n) {
    __shared__ int ws[4];
    int i = blockIdx.x * 256 + threadIdx.x;
    int lane = threadIdx.x & 63, wid = threadIdx.x >> 6;
    int v = (i < n) ? degi[i] : 0;
    int val = v;
#pragma unroll
    for (int off = 1; off < 64; off <<= 1) {
        int t = __shfl_up(val, off);
        if (lane >= off) val += t;
    }
    if (lane == 63) ws[wid] = val;
    __syncthreads();
    int woff = boff[blockIdx.x];
    for (int w = 0; w < wid; w++) woff += ws[w];
    if (i < n) {
        int ex = woff + val - v;
        rowptr[i] = ex;
        cursor[i] = ex;
    }
}

__global__ void fill_kernel(const int* __restrict__ src, const int* __restrict__ dst,
                            int* __restrict__ cursor, int* __restrict__ col, int E) {
    int e = blockIdx.x * blockDim.x + threadIdx.x;
    if (e < E) {
        int pos = atomicAdd(&cursor[dst[e]], 1);
        col[pos] = src[e];
    }
}

// ===================== agg1: mean of x rows over CSR =====================
__global__ void agg1_kernel(const float* __restrict__ x,
                            const int* __restrict__ rowptr, const int* __restrict__ col,
                            float* __restrict__ agg1, int n) {
    int gid  = blockIdx.x * blockDim.x + threadIdx.x;
    int node = gid >> 6;
    int lane = threadIdx.x & 63;
    if (node >= n) return;
    int beg = rowptr[node], end = rowptr[node + 1];
    float ax = 0.f, ay = 0.f;
    int j = beg;
    for (; j + 1 < end; j += 2) {
        int s0 = col[j], s1 = col[j + 1];
        float2 v0 = ((const float2*)(x + (size_t)s0 * IN_F))[lane];
        float2 v1 = ((const float2*)(x + (size_t)s1 * IN_F))[lane];
        ax += v0.x + v1.x;
        ay += v0.y + v1.y;
    }
    if (j < end) {
        float2 v0 = ((const float2*)(x + (size_t)col[j] * IN_F))[lane];
        ax += v0.x;
        ay += v0.y;
    }
    float inv = 1.0f / fmaxf((float)(end - beg), 1.0f);
    ((float2*)(agg1 + (size_t)node * IN_F))[lane] = make_float2(ax * inv, ay * inv);
}

// ===================== W split: f32 -> bf16 hi/lo, concat [W1l|W1r] k-major =====
__global__ __launch_bounds__(256) void split_w(const float* __restrict__ W1l,
                                               const float* __restrict__ W1r,
                                               unsigned short* __restrict__ Wh,
                                               unsigned short* __restrict__ Wl) {
    int idx = blockIdx.x * 256 + threadIdx.x;     // 0..65535 = feat*256 + k
    int feat = idx >> 8, k = idx & 255;
    float w = (k < IN_F) ? W1l[feat * IN_F + k] : W1r[feat * IN_F + (k - IN_F)];
    unsigned short h = f2bf(w);
    Wh[idx] = h;
    Wl[idx] = f2bf(w - bf2f(h));
}

// ===================== fused layer1 (split-bf16 MFMA) + layer2 projections =====
// C[128 nodes x 256 feats] = [agg1|x] @ [W1l|W1r]^T ; h = relu(C + b1);
// p = h.W2l, q = h.W2r (h never stored). 3-term split: AhWh + AlWh + AhWl.
__global__ __launch_bounds__(256, 2) void layer1_kernel(
        const float* __restrict__ x, const float* __restrict__ agg1,
        const unsigned short* __restrict__ Wh, const unsigned short* __restrict__ Wl,
        const float* __restrict__ b1l,
        const float* __restrict__ W2l, const float* __restrict__ W2r,
        float* __restrict__ p, float* __restrict__ q, int n) {
    __shared__ unsigned short Ah[128 * 32];   // [node][k] rows of 32 bf16 (64 B)
    __shared__ unsigned short Al[128 * 32];
    __shared__ unsigned short Bh[256 * 32];   // [feat][k]
    __shared__ unsigned short Bl[256 * 32];

    int tid  = threadIdx.x;
    int lane = tid & 63;
    int wv   = tid >> 6;          // wave 0..3: owns nodes wv*32 .. wv*32+31
    int m15  = lane & 15;
    int quad = lane >> 4;
    int node0 = blockIdx.x * 128;

    f32x4 acc[2][16];
#pragma unroll
    for (int nt = 0; nt < 2; nt++)
#pragma unroll
        for (int ft = 0; ft < 16; ft++) acc[nt][ft] = (f32x4){0.f, 0.f, 0.f, 0.f};

    int rown = tid >> 2;   // 0..63
    int sub  = tid & 3;

    for (int kc = 0; kc < 8; kc++) {
        int k0 = kc * 32;
        const float* Asrc = (kc < 4) ? agg1 : x;
        int aoff = (kc < 4) ? k0 : (k0 - IN_F);

        // ---- stage A (128 nodes x 32 k), f32 -> bf16 hi/lo ----
#pragma unroll
        for (int ps = 0; ps < 2; ps++) {
            int nl = ps * 64 + rown;
            int g  = node0 + nl;
            float4 v0 = make_float4(0.f, 0.f, 0.f, 0.f);
            float4 v1 = make_float4(0.f, 0.f, 0.f, 0.f);
            if (g < n) {
                const float* rp = Asrc + (size_t)g * IN_F + aoff + sub * 8;
                v0 = *(const float4*)rp;
                v1 = *(const float4*)(rp + 4);
            }
            float f[8] = {v0.x, v0.y, v0.z, v0.w, v1.x, v1.y, v1.z, v1.w};
            u16x8 hv, lv;
#pragma unroll
            for (int i = 0; i < 8; i++) {
                unsigned short hh = f2bf(f[i]);
                hv[i] = hh;
                lv[i] = f2bf(f[i] - bf2f(hh));
            }
            *(u16x8*)&Ah[nl * 32 + sub * 8] = hv;
            *(u16x8*)&Al[nl * 32 + sub * 8] = lv;
        }
        // ---- stage W chunk (256 feats x 32 k), already bf16 ----
#pragma unroll
        for (int ps = 0; ps < 4; ps++) {
            int feat = ps * 64 + rown;
            size_t go = (size_t)feat * 256 + k0 + sub * 8;
            *(u16x8*)&Bh[feat * 32 + sub * 8] = *(const u16x8*)(Wh + go);
            *(u16x8*)&Bl[feat * 32 + sub * 8] = *(const u16x8*)(Wl + go);
        }
        __syncthreads();

        // ---- MFMA: 2 node-tiles x 16 feat-tiles x 3 terms ----
        bf16x8 a0h = *(const bf16x8*)&Ah[(wv * 32 + m15) * 32 + quad * 8];
        bf16x8 a0l = *(const bf16x8*)&Al[(wv * 32 + m15) * 32 + quad * 8];
        bf16x8 a1h = *(const bf16x8*)&Ah[(wv * 32 + 16 + m15) * 32 + quad * 8];
        bf16x8 a1l = *(const bf16x8*)&Al[(wv * 32 + 16 + m15) * 32 + quad * 8];
#pragma unroll
        for (int ft = 0; ft < 16; ft++) {
            bf16x8 bh = *(const bf16x8*)&Bh[(ft * 16 + m15) * 32 + quad * 8];
            bf16x8 bl = *(const bf16x8*)&Bl[(ft * 16 + m15) * 32 + quad * 8];
            acc[0][ft] = __builtin_amdgcn_mfma_f32_16x16x32_bf16(a0h, bh, acc[0][ft], 0, 0, 0);
            acc[0][ft] = __builtin_amdgcn_mfma_f32_16x16x32_bf16(a0l, bh, acc[0][ft], 0, 0, 0);
            acc[0][ft] = __builtin_amdgcn_mfma_f32_16x16x32_bf16(a0h, bl, acc[0][ft], 0, 0, 0);
            acc[1][ft] = __builtin_amdgcn_mfma_f32_16x16x32_bf16(a1h, bh, acc[1][ft], 0, 0, 0);
            acc[1][ft] = __builtin_amdgcn_mfma_f32_16x16x32_bf16(a1l, bh, acc[1][ft], 0, 0, 0);
            acc[1][ft] = __builtin_amdgcn_mfma_f32_16x16x32_bf16(a1h, bl, acc[1][ft], 0, 0, 0);
        }
        __syncthreads();
    }

    // ---- epilogue: h = relu(C + b1); p = h.W2l, q = h.W2r per node ----
    // C/D layout: col(feat-in-tile)=lane&15, row(node-in-tile)=quad*4+reg
#pragma unroll
    for (int nt = 0; nt < 2; nt++) {
        float u0 = 0, u1 = 0, u2 = 0, u3 = 0;
        float v0 = 0, v1 = 0, v2 = 0, v3 = 0;
#pragma unroll
        for (int ft = 0; ft < 16; ft++) {
            int fj = ft * 16 + m15;
            float bb = b1l[fj], wl = W2l[fj], wr = W2r[fj];
            f32x4 c = acc[nt][ft];
            float h0 = fmaxf(c[0] + bb, 0.f);
            float h1 = fmaxf(c[1] + bb, 0.f);
            float h2 = fmaxf(c[2] + bb, 0.f);
            float h3 = fmaxf(c[3] + bb, 0.f);
            u0 += h0 * wl; v0 += h0 * wr;
            u1 += h1 * wl; v1 += h1 * wr;
            u2 += h2 * wl; v2 += h2 * wr;
            u3 += h3 * wl; v3 += h3 * wr;
        }
#pragma unroll
        for (int off = 1; off < 16; off <<= 1) {
            u0 += __shfl_xor(u0, off); v0 += __shfl_xor(v0, off);
            u1 += __shfl_xor(u1, off); v1 += __shfl_xor(v1, off);
            u2 += __shfl_xor(u2, off); v2 += __shfl_xor(v2, off);
            u3 += __shfl_xor(u3, off); v3 += __shfl_xor(v3, off);
        }
        if (m15 == 0) {
            int nb = node0 + wv * 32 + nt * 16 + quad * 4;
            if (nb + 0 < n) { p[nb + 0] = u0; q[nb + 0] = v0; }
            if (nb + 1 < n) { p[nb + 1] = u1; q[nb + 1] = v1; }
            if (nb + 2 < n) { p[nb + 2] = u2; q[nb + 2] = v2; }
            if (nb + 3 < n) { p[nb + 3] = u3; q[nb + 3] = v3; }
        }
    }
}

// ===================== final: out = mean(p[neigh]) + b2 + q =====================
__global__ void out_kernel(const float* __restrict__ p, const float* __restrict__ q,
                           const int* __restrict__ rowptr, const int* __restrict__ col,
                           const float* __restrict__ b2l,
                           float* __restrict__ out, int n) {
    int gid  = blockIdx.x * blockDim.x + threadIdx.x;
    int node = gid >> 6;
    int lane = threadIdx.x & 63;
    if (node >= n) return;
    int beg = rowptr[node], end = rowptr[node + 1];
    float s = 0.f;
    for (int j = beg + lane; j < end; j += 64) s += p[col[j]];
#pragma unroll
    for (int off = 32; off; off >>= 1) s += __shfl_down(s, off);
    if (lane == 0) {
        float inv = 1.0f / fmaxf((float)(end - beg), 1.0f);
        out[node] = s * inv + b2l[0] + q[node];
    }
}

extern "C" void kernel_launch(void* const* d_in, const int* in_sizes, int n_in,
                              void* d_out, int out_size, void* d_ws, size_t ws_size,
                              hipStream_t stream) {
    const float* x   = (const float*)d_in[0];
    const int*   ei  = (const int*)  d_in[1];
    const float* W1l = (const float*)d_in[2];
    const float* b1l = (const float*)d_in[3];
    const float* W1r = (const float*)d_in[4];
    const float* W2l = (const float*)d_in[5];
    const float* b2l = (const float*)d_in[6];
    const float* W2r = (const float*)d_in[7];
    float* out = (float*)d_out;

    int n = in_sizes[0] / IN_F;   // 50000
    int E = in_sizes[1] / 2;      // 800000
    const int* src = ei;
    const int* dst = ei + E;

    size_t n_pad = ((size_t)n + 256) & ~(size_t)255;
    int NB = (n + 255) / 256;

    int* degi   = (int*)d_ws;                          // n
    int* rowptr = degi + n_pad;                        // n+1
    int* cursor = rowptr + n_pad;                      // n
    int* bsum   = cursor + n_pad;                      // NB (<=1024)
    int* boff   = bsum + 1024;                         // NB
    int* col    = boff + 1024;                         // E
    unsigned short* Whs = (unsigned short*)(col + (((size_t)E + 255) & ~(size_t)255)); // 65536
    unsigned short* Wls = Whs + 65536;                 // 65536
    float* agg1 = (float*)(Wls + 65536);               // n*128
    float* p    = agg1 + (size_t)n * IN_F;
    float* q    = p + n_pad;

    hipMemsetAsync(degi, 0, sizeof(int) * (size_t)n, stream);

    degree_kernel<<<(E + 255) / 256, 256, 0, stream>>>(dst, degi, E);
    scan_part<<<NB, 256, 0, stream>>>(degi, bsum, n);
    scan_offsets<<<1, 1024, 0, stream>>>(bsum, boff, NB, rowptr, n, E);
    scan_apply<<<NB, 256, 0, stream>>>(degi, boff, rowptr, cursor, n);
    fill_kernel<<<(E + 255) / 256, 256, 0, stream>>>(src, dst, cursor, col, E);

    split_w<<<256, 256, 0, stream>>>(W1l, W1r, Whs, Wls);

    agg1_kernel<<<(int)(((size_t)n * 64 + 255) / 256), 256, 0, stream>>>(x, rowptr, col, agg1, n);

    layer1_kernel<<<(n + 127) / 128, 256, 0, stream>>>(
        x, agg1, Whs, Wls, b1l, W2l, W2r, p, q, n);

    out_kernel<<<(int)(((size_t)n * 64 + 255) / 256), 256, 0, stream>>>(
        p, q, rowptr, col, b2l, out, n);
}

// Round 5
// 263.918 us; speedup vs baseline: 14.6085x; 1.0268x over previous
//
#include <hip/hip_runtime.h>

static constexpr int IN_F = 128;

typedef __attribute__((ext_vector_type(8))) short bf16x8;
typedef __attribute__((ext_vector_type(8))) unsigned short u16x8;
typedef __attribute__((ext_vector_type(4))) float f32x4;

__device__ inline unsigned short f2bf(float f) {   // RNE f32->bf16
    unsigned u = __float_as_uint(f);
    u += 0x7FFF + ((u >> 16) & 1);
    return (unsigned short)(u >> 16);
}
__device__ inline float bf2f(unsigned short h) {
    return __uint_as_float(((unsigned)h) << 16);
}

// ===================== CSR construction =====================

__global__ void degree_kernel(const int* __restrict__ dst, int* __restrict__ degi, int E) {
    int e = blockIdx.x * blockDim.x + threadIdx.x;
    if (e < E) atomicAdd(&degi[dst[e]], 1);
}

__global__ __launch_bounds__(256) void scan_part(const int* __restrict__ degi,
                                                 int* __restrict__ bsum, int n) {
    __shared__ int ws[4];
    int i = blockIdx.x * 256 + threadIdx.x;
    int lane = threadIdx.x & 63, wid = threadIdx.x >> 6;
    int v = (i < n) ? degi[i] : 0;
#pragma unroll
    for (int off = 32; off; off >>= 1) v += __shfl_down(v, off);
    if (lane == 0) ws[wid] = v;
    __syncthreads();
    if (threadIdx.x == 0) bsum[blockIdx.x] = ws[0] + ws[1] + ws[2] + ws[3];
}

__global__ __launch_bounds__(1024) void scan_offsets(const int* __restrict__ bsum,
                                                     int* __restrict__ boff, int NB,
                                                     int* __restrict__ rowptr, int n, int E) {
    __shared__ int ws[16];
    int t = threadIdx.x;
    int lane = t & 63, wid = t >> 6;
    int v = (t < NB) ? bsum[t] : 0;
    int val = v;
#pragma unroll
    for (int off = 1; off < 64; off <<= 1) {
        int tt = __shfl_up(val, off);
        if (lane >= off) val += tt;
    }
    if (lane == 63) ws[wid] = val;
    __syncthreads();
    if (wid == 0 && lane < 16) {
        int s = ws[lane];
#pragma unroll
        for (int off = 1; off < 16; off <<= 1) {
            int tt = __shfl_up(s, off);
            if (lane >= off) s += tt;
        }
        ws[lane] = s;
    }
    __syncthreads();
    int woff = (wid > 0) ? ws[wid - 1] : 0;
    if (t < NB) boff[t] = woff + val - v;
    if (t == 0) rowptr[n] = E;
}

__global__ __launch_bounds__(256) void scan_apply(const int* __restrict__ degi,
                                                  const int* __restrict__ boff,
                                                  int* __restrict__ rowptr,
                                                  int* __restrict__ cursor, int n) {
    __shared__ int ws[4];
    int i = blockIdx.x * 256 + threadIdx.x;
    int lane = threadIdx.x & 63, wid = threadIdx.x >> 6;
    int v = (i < n) ? degi[i] : 0;
    int val = v;
#pragma unroll
    for (int off = 1; off < 64; off <<= 1) {
        int t = __shfl_up(val, off);
        if (lane >= off) val += t;
    }
    if (lane == 63) ws[wid] = val;
    __syncthreads();
    int woff = boff[blockIdx.x];
    for (int w = 0; w < wid; w++) woff += ws[w];
    if (i < n) {
        int ex = woff + val - v;
        rowptr[i] = ex;
        cursor[i] = ex;
    }
}

__global__ void fill_kernel(const int* __restrict__ src, const int* __restrict__ dst,
                            int* __restrict__ cursor, int* __restrict__ col, int E) {
    int e = blockIdx.x * blockDim.x + threadIdx.x;
    if (e < E) {
        int pos = atomicAdd(&cursor[dst[e]], 1);
        col[pos] = src[e];
    }
}

// ===================== split x: f32 -> bf16 hi/lo =====================
__global__ __launch_bounds__(256) void split_x(const float* __restrict__ x,
                                               unsigned short* __restrict__ xh,
                                               unsigned short* __restrict__ xl,
                                               long long total2) {
    long long i = (long long)blockIdx.x * 256 + threadIdx.x;   // pairs
    if (i >= total2) return;
    float2 v = ((const float2*)x)[i];
    unsigned short h0 = f2bf(v.x), h1 = f2bf(v.y);
    ((ushort2*)xh)[i] = make_ushort2(h0, h1);
    ((ushort2*)xl)[i] = make_ushort2(f2bf(v.x - bf2f(h0)), f2bf(v.y - bf2f(h1)));
}

// ===================== W split: f32 -> bf16 hi/lo, concat [W1l|W1r] k-major =====
__global__ __launch_bounds__(256) void split_w(const float* __restrict__ W1l,
                                               const float* __restrict__ W1r,
                                               unsigned short* __restrict__ Wh,
                                               unsigned short* __restrict__ Wl) {
    int idx = blockIdx.x * 256 + threadIdx.x;     // 0..65535 = feat*256 + k
    int feat = idx >> 8, k = idx & 255;
    float w = (k < IN_F) ? W1l[feat * IN_F + k] : W1r[feat * IN_F + (k - IN_F)];
    unsigned short h = f2bf(w);
    Wh[idx] = h;
    Wl[idx] = f2bf(w - bf2f(h));
}

// ===================== agg1: mean of x_hi rows over CSR -> bf16 hi/lo =====
__global__ void agg1_kernel(const unsigned short* __restrict__ xh,
                            const int* __restrict__ rowptr, const int* __restrict__ col,
                            unsigned short* __restrict__ aggh,
                            unsigned short* __restrict__ aggl, int n) {
    int gid  = blockIdx.x * blockDim.x + threadIdx.x;
    int node = gid >> 6;
    int lane = threadIdx.x & 63;
    if (node >= n) return;
    int beg = rowptr[node], end = rowptr[node + 1];
    float ax = 0.f, ay = 0.f;
    int j = beg;
    for (; j + 3 < end; j += 4) {
        int s0 = col[j], s1 = col[j + 1], s2 = col[j + 2], s3 = col[j + 3];
        ushort2 v0 = ((const ushort2*)(xh + (size_t)s0 * IN_F))[lane];
        ushort2 v1 = ((const ushort2*)(xh + (size_t)s1 * IN_F))[lane];
        ushort2 v2 = ((const ushort2*)(xh + (size_t)s2 * IN_F))[lane];
        ushort2 v3 = ((const ushort2*)(xh + (size_t)s3 * IN_F))[lane];
        ax += bf2f(v0.x) + bf2f(v1.x) + bf2f(v2.x) + bf2f(v3.x);
        ay += bf2f(v0.y) + bf2f(v1.y) + bf2f(v2.y) + bf2f(v3.y);
    }
    for (; j < end; j++) {
        ushort2 v0 = ((const ushort2*)(xh + (size_t)col[j] * IN_F))[lane];
        ax += bf2f(v0.x);
        ay += bf2f(v0.y);
    }
    float inv = 1.0f / fmaxf((float)(end - beg), 1.0f);
    float mx = ax * inv, my = ay * inv;
    unsigned short hx = f2bf(mx), hy = f2bf(my);
    ((ushort2*)(aggh + (size_t)node * IN_F))[lane] = make_ushort2(hx, hy);
    ((ushort2*)(aggl + (size_t)node * IN_F))[lane] =
        make_ushort2(f2bf(mx - bf2f(hx)), f2bf(my - bf2f(hy)));
}

// ===================== fused layer1 (split-bf16 MFMA) + layer2 projections =====
// C[128 nodes x 256 feats] = [agg1|x] @ [W1l|W1r]^T ; h = relu(C + b1);
// p = h.W2l, q = h.W2r (h never stored). 3-term split: AhWh + AlWh + AhWl.
__global__ __launch_bounds__(256, 2) void layer1_kernel(
        const unsigned short* __restrict__ xh, const unsigned short* __restrict__ xl,
        const unsigned short* __restrict__ aggh, const unsigned short* __restrict__ aggl,
        const unsigned short* __restrict__ Wh, const unsigned short* __restrict__ Wl,
        const float* __restrict__ b1l,
        const float* __restrict__ W2l, const float* __restrict__ W2r,
        float* __restrict__ p, float* __restrict__ q, int n) {
    __shared__ unsigned short Ah[128 * 32];   // [node][k] rows of 32 bf16 (64 B)
    __shared__ unsigned short Al[128 * 32];
    __shared__ unsigned short Bh[256 * 32];   // [feat][k]
    __shared__ unsigned short Bl[256 * 32];

    int tid  = threadIdx.x;
    int lane = tid & 63;
    int wv   = tid >> 6;          // wave 0..3: owns nodes wv*32 .. wv*32+31
    int m15  = lane & 15;
    int quad = lane >> 4;
    int node0 = blockIdx.x * 128;

    f32x4 acc[2][16];
#pragma unroll
    for (int nt = 0; nt < 2; nt++)
#pragma unroll
        for (int ft = 0; ft < 16; ft++) acc[nt][ft] = (f32x4){0.f, 0.f, 0.f, 0.f};

    int rown = tid >> 2;   // 0..63
    int sub  = tid & 3;

    for (int kc = 0; kc < 8; kc++) {
        int k0 = kc * 32;
        const unsigned short* Ahs = (kc < 4) ? aggh : xh;
        const unsigned short* Als = (kc < 4) ? aggl : xl;
        int aoff = (kc < 4) ? k0 : (k0 - IN_F);

        // ---- stage A (128 nodes x 32 k): pure ushort8 copies ----
#pragma unroll
        for (int ps = 0; ps < 2; ps++) {
            int nl = ps * 64 + rown;
            int g  = node0 + nl;
            u16x8 hv = {0,0,0,0,0,0,0,0}, lv = {0,0,0,0,0,0,0,0};
            if (g < n) {
                size_t go = (size_t)g * IN_F + aoff + sub * 8;
                hv = *(const u16x8*)(Ahs + go);
                lv = *(const u16x8*)(Als + go);
            }
            *(u16x8*)&Ah[nl * 32 + sub * 8] = hv;
            *(u16x8*)&Al[nl * 32 + sub * 8] = lv;
        }
        // ---- stage W chunk (256 feats x 32 k) ----
#pragma unroll
        for (int ps = 0; ps < 4; ps++) {
            int feat = ps * 64 + rown;
            size_t go = (size_t)feat * 256 + k0 + sub * 8;
            *(u16x8*)&Bh[feat * 32 + sub * 8] = *(const u16x8*)(Wh + go);
            *(u16x8*)&Bl[feat * 32 + sub * 8] = *(const u16x8*)(Wl + go);
        }
        __syncthreads();

        // ---- MFMA: 2 node-tiles x 16 feat-tiles x 3 terms ----
        bf16x8 a0h = *(const bf16x8*)&Ah[(wv * 32 + m15) * 32 + quad * 8];
        bf16x8 a0l = *(const bf16x8*)&Al[(wv * 32 + m15) * 32 + quad * 8];
        bf16x8 a1h = *(const bf16x8*)&Ah[(wv * 32 + 16 + m15) * 32 + quad * 8];
        bf16x8 a1l = *(const bf16x8*)&Al[(wv * 32 + 16 + m15) * 32 + quad * 8];
#pragma unroll
        for (int ft = 0; ft < 16; ft++) {
            bf16x8 bh = *(const bf16x8*)&Bh[(ft * 16 + m15) * 32 + quad * 8];
            bf16x8 bl = *(const bf16x8*)&Bl[(ft * 16 + m15) * 32 + quad * 8];
            acc[0][ft] = __builtin_amdgcn_mfma_f32_16x16x32_bf16(a0h, bh, acc[0][ft], 0, 0, 0);
            acc[0][ft] = __builtin_amdgcn_mfma_f32_16x16x32_bf16(a0l, bh, acc[0][ft], 0, 0, 0);
            acc[0][ft] = __builtin_amdgcn_mfma_f32_16x16x32_bf16(a0h, bl, acc[0][ft], 0, 0, 0);
            acc[1][ft] = __builtin_amdgcn_mfma_f32_16x16x32_bf16(a1h, bh, acc[1][ft], 0, 0, 0);
            acc[1][ft] = __builtin_amdgcn_mfma_f32_16x16x32_bf16(a1l, bh, acc[1][ft], 0, 0, 0);
            acc[1][ft] = __builtin_amdgcn_mfma_f32_16x16x32_bf16(a1h, bl, acc[1][ft], 0, 0, 0);
        }
        __syncthreads();
    }

    // ---- epilogue: h = relu(C + b1); p = h.W2l, q = h.W2r per node ----
    // C/D layout: col(feat-in-tile)=lane&15, row(node-in-tile)=quad*4+reg
#pragma unroll
    for (int nt = 0; nt < 2; nt++) {
        float u0 = 0, u1 = 0, u2 = 0, u3 = 0;
        float v0 = 0, v1 = 0, v2 = 0, v3 = 0;
#pragma unroll
        for (int ft = 0; ft < 16; ft++) {
            int fj = ft * 16 + m15;
            float bb = b1l[fj], wl = W2l[fj], wr = W2r[fj];
            f32x4 c = acc[nt][ft];
            float h0 = fmaxf(c[0] + bb, 0.f);
            float h1 = fmaxf(c[1] + bb, 0.f);
            float h2 = fmaxf(c[2] + bb, 0.f);
            float h3 = fmaxf(c[3] + bb, 0.f);
            u0 += h0 * wl; v0 += h0 * wr;
            u1 += h1 * wl; v1 += h1 * wr;
            u2 += h2 * wl; v2 += h2 * wr;
            u3 += h3 * wl; v3 += h3 * wr;
        }
#pragma unroll
        for (int off = 1; off < 16; off <<= 1) {
            u0 += __shfl_xor(u0, off); v0 += __shfl_xor(v0, off);
            u1 += __shfl_xor(u1, off); v1 += __shfl_xor(v1, off);
            u2 += __shfl_xor(u2, off); v2 += __shfl_xor(v2, off);
            u3 += __shfl_xor(u3, off); v3 += __shfl_xor(v3, off);
        }
        if (m15 == 0) {
            int nb = node0 + wv * 32 + nt * 16 + quad * 4;
            if (nb + 0 < n) { p[nb + 0] = u0; q[nb + 0] = v0; }
            if (nb + 1 < n) { p[nb + 1] = u1; q[nb + 1] = v1; }
            if (nb + 2 < n) { p[nb + 2] = u2; q[nb + 2] = v2; }
            if (nb + 3 < n) { p[nb + 3] = u3; q[nb + 3] = v3; }
        }
    }
}

// ===================== final: out = mean(p[neigh]) + b2 + q =====================
__global__ void out_kernel(const float* __restrict__ p, const float* __restrict__ q,
                           const int* __restrict__ rowptr, const int* __restrict__ col,
                           const float* __restrict__ b2l,
                           float* __restrict__ out, int n) {
    int gid  = blockIdx.x * blockDim.x + threadIdx.x;
    int node = gid >> 6;
    int lane = threadIdx.x & 63;
    if (node >= n) return;
    int beg = rowptr[node], end = rowptr[node + 1];
    float s = 0.f;
    for (int j = beg + lane; j < end; j += 64) s += p[col[j]];
#pragma unroll
    for (int off = 32; off; off >>= 1) s += __shfl_down(s, off);
    if (lane == 0) {
        float inv = 1.0f / fmaxf((float)(end - beg), 1.0f);
        out[node] = s * inv + b2l[0] + q[node];
    }
}

extern "C" void kernel_launch(void* const* d_in, const int* in_sizes, int n_in,
                              void* d_out, int out_size, void* d_ws, size_t ws_size,
                              hipStream_t stream) {
    const float* x   = (const float*)d_in[0];
    const int*   ei  = (const int*)  d_in[1];
    const float* W1l = (const float*)d_in[2];
    const float* b1l = (const float*)d_in[3];
    const float* W1r = (const float*)d_in[4];
    const float* W2l = (const float*)d_in[5];
    const float* b2l = (const float*)d_in[6];
    const float* W2r = (const float*)d_in[7];
    float* out = (float*)d_out;

    int n = in_sizes[0] / IN_F;   // 50000
    int E = in_sizes[1] / 2;      // 800000
    const int* src = ei;
    const int* dst = ei + E;

    size_t n_pad = ((size_t)n + 256) & ~(size_t)255;
    int NB = (n + 255) / 256;

    int* degi   = (int*)d_ws;                          // n
    int* rowptr = degi + n_pad;                        // n+1
    int* cursor = rowptr + n_pad;                      // n
    int* bsum   = cursor + n_pad;                      // NB (<=1024)
    int* boff   = bsum + 1024;                         // NB
    int* col    = boff + 1024;                         // E
    unsigned short* Whs = (unsigned short*)(col + (((size_t)E + 255) & ~(size_t)255)); // 65536
    unsigned short* Wls  = Whs + 65536;
    unsigned short* xh   = Wls + 65536;                // n*128
    unsigned short* xl   = xh + (size_t)n * IN_F;
    unsigned short* aggh = xl + (size_t)n * IN_F;
    unsigned short* aggl = aggh + (size_t)n * IN_F;
    float* p = (float*)(aggl + (size_t)n * IN_F);
    float* q = p + n_pad;

    hipMemsetAsync(degi, 0, sizeof(int) * (size_t)n, stream);

    degree_kernel<<<(E + 255) / 256, 256, 0, stream>>>(dst, degi, E);
    scan_part<<<NB, 256, 0, stream>>>(degi, bsum, n);
    scan_offsets<<<1, 1024, 0, stream>>>(bsum, boff, NB, rowptr, n, E);
    scan_apply<<<NB, 256, 0, stream>>>(degi, boff, rowptr, cursor, n);
    fill_kernel<<<(E + 255) / 256, 256, 0, stream>>>(src, dst, cursor, col, E);

    long long total2 = (long long)n * IN_F / 2;
    split_x<<<(int)((total2 + 255) / 256), 256, 0, stream>>>(x, xh, xl, total2);
    split_w<<<256, 256, 0, stream>>>(W1l, W1r, Whs, Wls);

    agg1_kernel<<<(int)(((size_t)n * 64 + 255) / 256), 256, 0, stream>>>(
        xh, rowptr, col, aggh, aggl, n);

    layer1_kernel<<<(n + 127) / 128, 256, 0, stream>>>(
        xh, xl, aggh, aggl, Whs, Wls, b1l, W2l, W2r, p, q, n);

    out_kernel<<<(int)(((size_t)n * 64 + 255) / 256), 256, 0, stream>>>(
        p, q, rowptr, col, b2l, out, n);
}

// Round 6
// 195.807 us; speedup vs baseline: 19.6900x; 1.3478x over previous
//
#include <hip/hip_runtime.h>

static constexpr int IN_F = 128;

typedef __attribute__((ext_vector_type(8))) short bf16x8;
typedef __attribute__((ext_vector_type(8))) unsigned short u16x8;
typedef __attribute__((ext_vector_type(4))) float f32x4;

__device__ inline unsigned short f2bf(float f) {   // RNE f32->bf16
    unsigned u = __float_as_uint(f);
    u += 0x7FFF + ((u >> 16) & 1);
    return (unsigned short)(u >> 16);
}
__device__ inline float bf2f(unsigned short h) {
    return __uint_as_float(((unsigned)h) << 16);
}

// ===================== CSR via two-level bucket sort =====================
// bucket = dst >> 8 (256 nodes per bucket). Requires n < 65536 (n = 50000).
// Edge packed as (dst << 16) | src in 32 bits.

__global__ __launch_bounds__(256) void bin_count(const int* __restrict__ dst,
                                                 int* __restrict__ bcnt, int E, int nbk) {
    __shared__ int h[256];
    int tid = threadIdx.x;
    h[tid] = 0;
    __syncthreads();
    int base = blockIdx.x * 4096;
#pragma unroll
    for (int r = 0; r < 16; r++) {
        int e = base + r * 256 + tid;
        if (e < E) atomicAdd(&h[((unsigned)dst[e]) >> 8], 1);
    }
    __syncthreads();
    if (tid < nbk && h[tid] > 0) atomicAdd(&bcnt[tid], h[tid]);
}

__global__ __launch_bounds__(256) void bucket_scan(const int* __restrict__ bcnt,
                                                   int* __restrict__ boff,
                                                   int* __restrict__ bcur, int nbk) {
    __shared__ int ws[4];
    int tid = threadIdx.x, lane = tid & 63, wid = tid >> 6;
    int v = (tid < nbk) ? bcnt[tid] : 0;
    int val = v;
#pragma unroll
    for (int off = 1; off < 64; off <<= 1) {
        int t = __shfl_up(val, off);
        if (lane >= off) val += t;
    }
    if (lane == 63) ws[wid] = val;
    __syncthreads();
    int pre = 0;
    for (int w = 0; w < wid; w++) pre += ws[w];
    int ex = pre + val - v;
    if (tid < nbk) { boff[tid] = ex; bcur[tid] = ex; }
}

__global__ __launch_bounds__(256) void bin_scatter(const int* __restrict__ src,
        const int* __restrict__ dst, int* __restrict__ bcur,
        unsigned* __restrict__ btmp, int E, int nbk) {
    __shared__ unsigned stage[4096];
    __shared__ int h[256];
    __shared__ int gbase[256];
    __shared__ int lcur[256];
    int tid = threadIdx.x;
    int base = blockIdx.x * 4096;
    h[tid] = 0;
    lcur[tid] = 0;
    __syncthreads();
#pragma unroll
    for (int r = 0; r < 16; r++) {
        int e = base + r * 256 + tid;
        if (e < E) {
            unsigned d = (unsigned)dst[e];
            stage[r * 256 + tid] = (d << 16) | (unsigned)src[e];
            atomicAdd(&h[d >> 8], 1);
        }
    }
    __syncthreads();
    if (tid < nbk && h[tid] > 0) gbase[tid] = atomicAdd(&bcur[tid], h[tid]);
    __syncthreads();
#pragma unroll
    for (int r = 0; r < 16; r++) {
        int e = base + r * 256 + tid;
        if (e < E) {
            unsigned pk = stage[r * 256 + tid];
            int bkt = pk >> 24;                    // dst >> 8
            int pos = gbase[bkt] + atomicAdd(&lcur[bkt], 1);
            btmp[pos] = pk;                        // run-local: merges in this XCD's L2
        }
    }
}

static constexpr int CSR_CAP = 5376;   // avg bucket ~4096 edges; 5376 >> 20 sigma

__global__ __launch_bounds__(256) void bucket_csr(const unsigned* __restrict__ btmp,
        const int* __restrict__ boff, const int* __restrict__ bcnt,
        int* __restrict__ rowptr, int* __restrict__ col, int n, int E) {
    __shared__ unsigned stage[CSR_CAP];
    __shared__ unsigned colL[CSR_CAP];
    __shared__ int cntL[256];
    __shared__ int curL[256];
    __shared__ int ws[4];
    int b = blockIdx.x;
    int tid = threadIdx.x, lane = tid & 63, wid = tid >> 6;
    int base = boff[b], cnt = bcnt[b];
    cntL[tid] = 0;
    __syncthreads();
    bool fits = (cnt <= CSR_CAP);
    if (fits) {
        for (int i = tid; i < cnt; i += 256) {
            unsigned pk = btmp[base + i];
            stage[i] = pk;
            atomicAdd(&cntL[(pk >> 16) & 255], 1);
        }
    } else {
        for (int i = tid; i < cnt; i += 256) {
            unsigned pk = btmp[base + i];
            atomicAdd(&cntL[(pk >> 16) & 255], 1);
        }
    }
    __syncthreads();
    int v = cntL[tid];
    int val = v;
#pragma unroll
    for (int off = 1; off < 64; off <<= 1) {
        int t = __shfl_up(val, off);
        if (lane >= off) val += t;
    }
    if (lane == 63) ws[wid] = val;
    __syncthreads();
    int pre = 0;
    for (int w = 0; w < wid; w++) pre += ws[w];
    int ex = pre + val - v;            // exclusive prefix within bucket
    curL[tid] = ex;
    int node = b * 256 + tid;
    if (node < n) rowptr[node] = base + ex;
    if (b == 0 && tid == 0) rowptr[n] = E;
    __syncthreads();
    if (fits) {
        for (int i = tid; i < cnt; i += 256) {
            unsigned pk = stage[i];
            int pos = atomicAdd(&curL[(pk >> 16) & 255], 1);
            colL[pos] = pk & 0xFFFFu;
        }
        __syncthreads();
        for (int i = tid; i < cnt; i += 256) col[base + i] = (int)colL[i];
    } else {   // overflow fallback (never for this data): direct scattered writes
        for (int i = tid; i < cnt; i += 256) {
            unsigned pk = btmp[base + i];
            int pos = atomicAdd(&curL[(pk >> 16) & 255], 1);
            col[base + pos] = (int)(pk & 0xFFFFu);
        }
    }
}

// ===================== split x: f32 -> bf16 hi/lo =====================
__global__ __launch_bounds__(256) void split_x(const float* __restrict__ x,
                                               unsigned short* __restrict__ xh,
                                               unsigned short* __restrict__ xl,
                                               long long total2) {
    long long i = (long long)blockIdx.x * 256 + threadIdx.x;   // pairs
    if (i >= total2) return;
    float2 v = ((const float2*)x)[i];
    unsigned short h0 = f2bf(v.x), h1 = f2bf(v.y);
    ((ushort2*)xh)[i] = make_ushort2(h0, h1);
    ((ushort2*)xl)[i] = make_ushort2(f2bf(v.x - bf2f(h0)), f2bf(v.y - bf2f(h1)));
}

// ===================== W split: f32 -> bf16 hi/lo, concat [W1l|W1r] k-major =====
__global__ __launch_bounds__(256) void split_w(const float* __restrict__ W1l,
                                               const float* __restrict__ W1r,
                                               unsigned short* __restrict__ Wh,
                                               unsigned short* __restrict__ Wl) {
    int idx = blockIdx.x * 256 + threadIdx.x;     // 0..65535 = feat*256 + k
    int feat = idx >> 8, k = idx & 255;
    float w = (k < IN_F) ? W1l[feat * IN_F + k] : W1r[feat * IN_F + (k - IN_F)];
    unsigned short h = f2bf(w);
    Wh[idx] = h;
    Wl[idx] = f2bf(w - bf2f(h));
}

// ===================== agg1: mean of x_hi rows over CSR -> bf16 hi/lo =====
__global__ void agg1_kernel(const unsigned short* __restrict__ xh,
                            const int* __restrict__ rowptr, const int* __restrict__ col,
                            unsigned short* __restrict__ aggh,
                            unsigned short* __restrict__ aggl, int n) {
    int gid  = blockIdx.x * blockDim.x + threadIdx.x;
    int node = gid >> 6;
    int lane = threadIdx.x & 63;
    if (node >= n) return;
    int beg = rowptr[node], end = rowptr[node + 1];
    float ax = 0.f, ay = 0.f;
    int j = beg;
    for (; j + 3 < end; j += 4) {
        int s0 = col[j], s1 = col[j + 1], s2 = col[j + 2], s3 = col[j + 3];
        ushort2 v0 = ((const ushort2*)(xh + (size_t)s0 * IN_F))[lane];
        ushort2 v1 = ((const ushort2*)(xh + (size_t)s1 * IN_F))[lane];
        ushort2 v2 = ((const ushort2*)(xh + (size_t)s2 * IN_F))[lane];
        ushort2 v3 = ((const ushort2*)(xh + (size_t)s3 * IN_F))[lane];
        ax += bf2f(v0.x) + bf2f(v1.x) + bf2f(v2.x) + bf2f(v3.x);
        ay += bf2f(v0.y) + bf2f(v1.y) + bf2f(v2.y) + bf2f(v3.y);
    }
    for (; j < end; j++) {
        ushort2 v0 = ((const ushort2*)(xh + (size_t)col[j] * IN_F))[lane];
        ax += bf2f(v0.x);
        ay += bf2f(v0.y);
    }
    float inv = 1.0f / fmaxf((float)(end - beg), 1.0f);
    float mx = ax * inv, my = ay * inv;
    unsigned short hx = f2bf(mx), hy = f2bf(my);
    ((ushort2*)(aggh + (size_t)node * IN_F))[lane] = make_ushort2(hx, hy);
    ((ushort2*)(aggl + (size_t)node * IN_F))[lane] =
        make_ushort2(f2bf(mx - bf2f(hx)), f2bf(my - bf2f(hy)));
}

// ===================== fused layer1 (split-bf16 MFMA) + layer2 projections =====
__global__ __launch_bounds__(256, 2) void layer1_kernel(
        const unsigned short* __restrict__ xh, const unsigned short* __restrict__ xl,
        const unsigned short* __restrict__ aggh, const unsigned short* __restrict__ aggl,
        const unsigned short* __restrict__ Wh, const unsigned short* __restrict__ Wl,
        const float* __restrict__ b1l,
        const float* __restrict__ W2l, const float* __restrict__ W2r,
        float* __restrict__ p, float* __restrict__ q, int n) {
    __shared__ unsigned short Ah[128 * 32];   // [node][k] rows of 32 bf16 (64 B)
    __shared__ unsigned short Al[128 * 32];
    __shared__ unsigned short Bh[256 * 32];   // [feat][k]
    __shared__ unsigned short Bl[256 * 32];

    int tid  = threadIdx.x;
    int lane = tid & 63;
    int wv   = tid >> 6;
    int m15  = lane & 15;
    int quad = lane >> 4;
    int node0 = blockIdx.x * 128;

    f32x4 acc[2][16];
#pragma unroll
    for (int nt = 0; nt < 2; nt++)
#pragma unroll
        for (int ft = 0; ft < 16; ft++) acc[nt][ft] = (f32x4){0.f, 0.f, 0.f, 0.f};

    int rown = tid >> 2;   // 0..63
    int sub  = tid & 3;

    for (int kc = 0; kc < 8; kc++) {
        int k0 = kc * 32;
        const unsigned short* Ahs = (kc < 4) ? aggh : xh;
        const unsigned short* Als = (kc < 4) ? aggl : xl;
        int aoff = (kc < 4) ? k0 : (k0 - IN_F);

#pragma unroll
        for (int ps = 0; ps < 2; ps++) {
            int nl = ps * 64 + rown;
            int g  = node0 + nl;
            u16x8 hv = {0,0,0,0,0,0,0,0}, lv = {0,0,0,0,0,0,0,0};
            if (g < n) {
                size_t go = (size_t)g * IN_F + aoff + sub * 8;
                hv = *(const u16x8*)(Ahs + go);
                lv = *(const u16x8*)(Als + go);
            }
            *(u16x8*)&Ah[nl * 32 + sub * 8] = hv;
            *(u16x8*)&Al[nl * 32 + sub * 8] = lv;
        }
#pragma unroll
        for (int ps = 0; ps < 4; ps++) {
            int feat = ps * 64 + rown;
            size_t go = (size_t)feat * 256 + k0 + sub * 8;
            *(u16x8*)&Bh[feat * 32 + sub * 8] = *(const u16x8*)(Wh + go);
            *(u16x8*)&Bl[feat * 32 + sub * 8] = *(const u16x8*)(Wl + go);
        }
        __syncthreads();

        bf16x8 a0h = *(const bf16x8*)&Ah[(wv * 32 + m15) * 32 + quad * 8];
        bf16x8 a0l = *(const bf16x8*)&Al[(wv * 32 + m15) * 32 + quad * 8];
        bf16x8 a1h = *(const bf16x8*)&Ah[(wv * 32 + 16 + m15) * 32 + quad * 8];
        bf16x8 a1l = *(const bf16x8*)&Al[(wv * 32 + 16 + m15) * 32 + quad * 8];
#pragma unroll
        for (int ft = 0; ft < 16; ft++) {
            bf16x8 bh = *(const bf16x8*)&Bh[(ft * 16 + m15) * 32 + quad * 8];
            bf16x8 bl = *(const bf16x8*)&Bl[(ft * 16 + m15) * 32 + quad * 8];
            acc[0][ft] = __builtin_amdgcn_mfma_f32_16x16x32_bf16(a0h, bh, acc[0][ft], 0, 0, 0);
            acc[0][ft] = __builtin_amdgcn_mfma_f32_16x16x32_bf16(a0l, bh, acc[0][ft], 0, 0, 0);
            acc[0][ft] = __builtin_amdgcn_mfma_f32_16x16x32_bf16(a0h, bl, acc[0][ft], 0, 0, 0);
            acc[1][ft] = __builtin_amdgcn_mfma_f32_16x16x32_bf16(a1h, bh, acc[1][ft], 0, 0, 0);
            acc[1][ft] = __builtin_amdgcn_mfma_f32_16x16x32_bf16(a1l, bh, acc[1][ft], 0, 0, 0);
            acc[1][ft] = __builtin_amdgcn_mfma_f32_16x16x32_bf16(a1h, bl, acc[1][ft], 0, 0, 0);
        }
        __syncthreads();
    }

    // C/D layout: col(feat-in-tile)=lane&15, row(node-in-tile)=quad*4+reg
#pragma unroll
    for (int nt = 0; nt < 2; nt++) {
        float u0 = 0, u1 = 0, u2 = 0, u3 = 0;
        float v0 = 0, v1 = 0, v2 = 0, v3 = 0;
#pragma unroll
        for (int ft = 0; ft < 16; ft++) {
            int fj = ft * 16 + m15;
            float bb = b1l[fj], wl = W2l[fj], wr = W2r[fj];
            f32x4 c = acc[nt][ft];
            float h0 = fmaxf(c[0] + bb, 0.f);
            float h1 = fmaxf(c[1] + bb, 0.f);
            float h2 = fmaxf(c[2] + bb, 0.f);
            float h3 = fmaxf(c[3] + bb, 0.f);
            u0 += h0 * wl; v0 += h0 * wr;
            u1 += h1 * wl; v1 += h1 * wr;
            u2 += h2 * wl; v2 += h2 * wr;
            u3 += h3 * wl; v3 += h3 * wr;
        }
#pragma unroll
        for (int off = 1; off < 16; off <<= 1) {
            u0 += __shfl_xor(u0, off); v0 += __shfl_xor(v0, off);
            u1 += __shfl_xor(u1, off); v1 += __shfl_xor(v1, off);
            u2 += __shfl_xor(u2, off); v2 += __shfl_xor(v2, off);
            u3 += __shfl_xor(u3, off); v3 += __shfl_xor(v3, off);
        }
        if (m15 == 0) {
            int nb = node0 + wv * 32 + nt * 16 + quad * 4;
            if (nb + 0 < n) { p[nb + 0] = u0; q[nb + 0] = v0; }
            if (nb + 1 < n) { p[nb + 1] = u1; q[nb + 1] = v1; }
            if (nb + 2 < n) { p[nb + 2] = u2; q[nb + 2] = v2; }
            if (nb + 3 < n) { p[nb + 3] = u3; q[nb + 3] = v3; }
        }
    }
}

// ===================== final: out = mean(p[neigh]) + b2 + q; 16 lanes/node =====
__global__ void out_kernel(const float* __restrict__ p, const float* __restrict__ q,
                           const int* __restrict__ rowptr, const int* __restrict__ col,
                           const float* __restrict__ b2l,
                           float* __restrict__ out, int n) {
    int gid  = blockIdx.x * blockDim.x + threadIdx.x;
    int node = gid >> 4;
    int l    = threadIdx.x & 15;
    if (node >= n) return;
    int beg = rowptr[node], end = rowptr[node + 1];
    float s = 0.f;
    for (int j = beg + l; j < end; j += 16) s += p[col[j]];
#pragma unroll
    for (int off = 8; off; off >>= 1) s += __shfl_xor(s, off);
    if (l == 0) {
        float inv = 1.0f / fmaxf((float)(end - beg), 1.0f);
        out[node] = s * inv + b2l[0] + q[node];
    }
}

extern "C" void kernel_launch(void* const* d_in, const int* in_sizes, int n_in,
                              void* d_out, int out_size, void* d_ws, size_t ws_size,
                              hipStream_t stream) {
    const float* x   = (const float*)d_in[0];
    const int*   ei  = (const int*)  d_in[1];
    const float* W1l = (const float*)d_in[2];
    const float* b1l = (const float*)d_in[3];
    const float* W1r = (const float*)d_in[4];
    const float* W2l = (const float*)d_in[5];
    const float* b2l = (const float*)d_in[6];
    const float* W2r = (const float*)d_in[7];
    float* out = (float*)d_out;

    int n = in_sizes[0] / IN_F;   // 50000 (< 65536 required by edge packing)
    int E = in_sizes[1] / 2;      // 800000
    const int* src = ei;
    const int* dst = ei + E;

    size_t n_pad = ((size_t)n + 256) & ~(size_t)255;
    int nbk = (n + 255) >> 8;                 // 196 buckets
    int nblk_e = (E + 4095) / 4096;           // 196 edge-chunk blocks

    int* bcnt   = (int*)d_ws;                           // 256
    int* boff   = bcnt + 256;                           // 256
    int* bcur   = boff + 256;                           // 256
    int* rowptr = bcur + 256;                           // n+1 (padded)
    unsigned* btmp = (unsigned*)(rowptr + n_pad);       // E
    int* col    = (int*)(btmp + (((size_t)E + 255) & ~(size_t)255));  // E
    unsigned short* Whs = (unsigned short*)(col + (((size_t)E + 255) & ~(size_t)255));
    unsigned short* Wls  = Whs + 65536;
    unsigned short* xh   = Wls + 65536;                 // n*128
    unsigned short* xl   = xh + (size_t)n * IN_F;
    unsigned short* aggh = xl + (size_t)n * IN_F;
    unsigned short* aggl = aggh + (size_t)n * IN_F;
    float* p = (float*)(aggl + (size_t)n * IN_F);
    float* q = p + n_pad;

    hipMemsetAsync(bcnt, 0, sizeof(int) * 256, stream);

    bin_count<<<nblk_e, 256, 0, stream>>>(dst, bcnt, E, nbk);
    bucket_scan<<<1, 256, 0, stream>>>(bcnt, boff, bcur, nbk);
    bin_scatter<<<nblk_e, 256, 0, stream>>>(src, dst, bcur, btmp, E, nbk);
    bucket_csr<<<nbk, 256, 0, stream>>>(btmp, boff, bcnt, rowptr, col, n, E);

    long long total2 = (long long)n * IN_F / 2;
    split_x<<<(int)((total2 + 255) / 256), 256, 0, stream>>>(x, xh, xl, total2);
    split_w<<<256, 256, 0, stream>>>(W1l, W1r, Whs, Wls);

    agg1_kernel<<<(int)(((size_t)n * 64 + 255) / 256), 256, 0, stream>>>(
        xh, rowptr, col, aggh, aggl, n);

    layer1_kernel<<<(n + 127) / 128, 256, 0, stream>>>(
        xh, xl, aggh, aggl, Whs, Wls, b1l, W2l, W2r, p, q, n);

    out_kernel<<<(int)(((size_t)n * 16 + 255) / 256), 256, 0, stream>>>(
        p, q, rowptr, col, b2l, out, n);
}

// Round 7
// 188.399 us; speedup vs baseline: 20.4643x; 1.0393x over previous
//
#include <hip/hip_runtime.h>

static constexpr int IN_F   = 128;
static constexpr int ECH    = 4096;   // edges per edge_bin block
static constexpr int RSLOT  = 64;     // btmp slots per (chunk,bucket); mean 20.9, +9sigma safe
static constexpr int CAPB   = 5376;   // col capacity per bucket (mean 4096, +20sigma)
static constexpr int CSR_CAP = 5376;
static constexpr int OVF_CAP = 4096;

typedef __attribute__((ext_vector_type(8))) short bf16x8;
typedef __attribute__((ext_vector_type(8))) unsigned short u16x8;
typedef __attribute__((ext_vector_type(4))) float f32x4;

__device__ inline unsigned short f2bf(float f) {   // RNE f32->bf16
    unsigned u = __float_as_uint(f);
    u += 0x7FFF + ((u >> 16) & 1);
    return (unsigned short)(u >> 16);
}
__device__ inline float bf2f(unsigned short h) {
    return __uint_as_float(((unsigned)h) << 16);
}

// ===================== CSR stage 1: bin edges into static (chunk,bucket) slots ====
// bucket = dst >> 8; edge packed (dst<<16)|src (requires n < 65536; n = 50000).
__global__ __launch_bounds__(256) void edge_bin(const int* __restrict__ src,
        const int* __restrict__ dst, unsigned* __restrict__ btmp,
        int* __restrict__ rcnt, int* __restrict__ ovf_cnt, unsigned* __restrict__ ovf,
        int E) {
    __shared__ unsigned stage[ECH];
    __shared__ int h[256], lcur[256];
    int tid = threadIdx.x, eb = blockIdx.x;
    int base = eb * ECH;
    h[tid] = 0; lcur[tid] = 0;
    __syncthreads();
#pragma unroll
    for (int r = 0; r < ECH / 256; r++) {
        int e = base + r * 256 + tid;
        if (e < E) {
            unsigned d = (unsigned)dst[e];
            stage[r * 256 + tid] = (d << 16) | (unsigned)src[e];
            atomicAdd(&h[d >> 8], 1);
        }
    }
    __syncthreads();
    int hv = h[tid];
    rcnt[eb * 256 + tid] = hv < RSLOT ? hv : RSLOT;   // contiguous 1KB write per block
#pragma unroll
    for (int r = 0; r < ECH / 256; r++) {
        int e = base + r * 256 + tid;
        if (e < E) {
            unsigned pk = stage[r * 256 + tid];
            int bkt = pk >> 24;
            int rank = atomicAdd(&lcur[bkt], 1);
            if (rank < RSLOT)
                btmp[(size_t)(eb * 256 + bkt) * RSLOT + rank] = pk;
            else {
                int pos = atomicAdd(ovf_cnt, 1);
                if (pos < OVF_CAP) ovf[pos] = pk;
            }
        }
    }
}

// ===================== CSR stage 2: per-bucket compact + local CSR =====================
__global__ __launch_bounds__(256) void bucket_csr(const unsigned* __restrict__ btmp,
        const int* __restrict__ rcnt, const int* __restrict__ ovf_cnt,
        const unsigned* __restrict__ ovf,
        int* __restrict__ rowbeg, int* __restrict__ degn, int* __restrict__ col,
        int n, int nblk) {
    __shared__ unsigned stage[CSR_CAP];
    __shared__ unsigned colL[CSR_CAP];
    __shared__ int cntL[256], curL[256];
    __shared__ int ws[4];
    __shared__ int s_extra;
    int b = blockIdx.x, tid = threadIdx.x, lane = tid & 63, wid = tid >> 6;

    // --- scan run counts of this bucket across nblk chunks ---
    int rc = (tid < nblk) ? rcnt[tid * 256 + b] : 0;
    int val = rc;
#pragma unroll
    for (int off = 1; off < 64; off <<= 1) {
        int t = __shfl_up(val, off);
        if (lane >= off) val += t;
    }
    if (lane == 63) ws[wid] = val;
    if (tid == 0) s_extra = 0;
    cntL[tid] = 0;
    __syncthreads();
    int pre = 0;
    for (int w = 0; w < wid; w++) pre += ws[w];
    int rb  = pre + val - rc;                       // run base in stage
    int cnt = ws[0] + ws[1] + ws[2] + ws[3];
    // --- copy runs into LDS (thread t copies chunk t's run) ---
    if (tid < nblk && rc > 0) {
        const unsigned* sp = btmp + (size_t)(tid * 256 + b) * RSLOT;
        for (int i = 0; i < rc; i++) stage[rb + i] = sp[i];
    }
    __syncthreads();
    // --- overflow append (statistically never) ---
    int novf = *ovf_cnt;
    if (novf > 0) {
        if (novf > OVF_CAP) novf = OVF_CAP;
        for (int i = tid; i < novf; i += 256) {
            unsigned pk = ovf[i];
            if ((int)(pk >> 24) == b) {
                int pos = atomicAdd(&s_extra, 1);
                if (cnt + pos < CSR_CAP) stage[cnt + pos] = pk;
            }
        }
    }
    __syncthreads();
    cnt += s_extra;
    if (cnt > CSR_CAP) cnt = CSR_CAP;
    // --- local node histogram ---
    for (int i = tid; i < cnt; i += 256) atomicAdd(&cntL[(stage[i] >> 16) & 255], 1);
    __syncthreads();
    int v = cntL[tid];
    int val2 = v;
#pragma unroll
    for (int off = 1; off < 64; off <<= 1) {
        int t = __shfl_up(val2, off);
        if (lane >= off) val2 += t;
    }
    if (lane == 63) ws[wid] = val2;
    __syncthreads();
    pre = 0;
    for (int w = 0; w < wid; w++) pre += ws[w];
    int ex = pre + val2 - v;
    curL[tid] = ex;
    int node = b * 256 + tid;
    if (node < n) { rowbeg[node] = b * CAPB + ex; degn[node] = v; }
    __syncthreads();
    for (int i = tid; i < cnt; i += 256) {
        unsigned pk = stage[i];
        int pos = atomicAdd(&curL[(pk >> 16) & 255], 1);
        colL[pos] = pk & 0xFFFFu;
    }
    __syncthreads();
    for (int i = tid; i < cnt; i += 256) col[b * CAPB + i] = (int)colL[i];
}

// ===================== fused split of x (hi/lo) and W (hi/lo, k-major concat) =====
__global__ __launch_bounds__(256) void split_xw(const float* __restrict__ x,
        const float* __restrict__ W1l, const float* __restrict__ W1r,
        unsigned short* __restrict__ xh, unsigned short* __restrict__ xl,
        unsigned short* __restrict__ Wh, unsigned short* __restrict__ Wl,
        long long total2) {
    long long i = (long long)blockIdx.x * 256 + threadIdx.x;
    if (i < total2) {
        float2 v = ((const float2*)x)[i];
        unsigned short h0 = f2bf(v.x), h1 = f2bf(v.y);
        ((ushort2*)xh)[i] = make_ushort2(h0, h1);
        ((ushort2*)xl)[i] = make_ushort2(f2bf(v.x - bf2f(h0)), f2bf(v.y - bf2f(h1)));
    } else {
        long long wi = i - total2;
        if (wi < 65536) {
            int feat = (int)(wi >> 8), k = (int)(wi & 255);
            float w = (k < IN_F) ? W1l[feat * IN_F + k] : W1r[feat * IN_F + (k - IN_F)];
            unsigned short h = f2bf(w);
            Wh[wi] = h;
            Wl[wi] = f2bf(w - bf2f(h));
        }
    }
}

// ===================== agg1: mean of x_hi rows; 1 wave/node, 2 rows per instr =====
__global__ void agg1_kernel(const unsigned short* __restrict__ xh,
                            const int* __restrict__ rowbeg, const int* __restrict__ degn,
                            const int* __restrict__ col,
                            unsigned short* __restrict__ aggh,
                            unsigned short* __restrict__ aggl, int n) {
    int gid  = blockIdx.x * blockDim.x + threadIdx.x;
    int node = gid >> 6;
    int lane = threadIdx.x & 63;
    if (node >= n) return;
    int beg = rowbeg[node], dg = degn[node], end = beg + dg;
    int half = lane >> 5, l32 = lane & 31;
    float a0 = 0.f, a1 = 0.f, a2 = 0.f, a3 = 0.f;
    int j = beg;
    for (; j + 3 < end; j += 4) {
        int s0 = col[j + half], s1 = col[j + 2 + half];
        ushort4 v0 = ((const ushort4*)(xh + (size_t)s0 * IN_F))[l32];
        ushort4 v1 = ((const ushort4*)(xh + (size_t)s1 * IN_F))[l32];
        a0 += bf2f(v0.x) + bf2f(v1.x);
        a1 += bf2f(v0.y) + bf2f(v1.y);
        a2 += bf2f(v0.z) + bf2f(v1.z);
        a3 += bf2f(v0.w) + bf2f(v1.w);
    }
    if (j + 1 < end) {
        int s0 = col[j + half];
        ushort4 v0 = ((const ushort4*)(xh + (size_t)s0 * IN_F))[l32];
        a0 += bf2f(v0.x); a1 += bf2f(v0.y); a2 += bf2f(v0.z); a3 += bf2f(v0.w);
        j += 2;
    }
    if (j < end && half == 0) {
        int s0 = col[j];
        ushort4 v0 = ((const ushort4*)(xh + (size_t)s0 * IN_F))[l32];
        a0 += bf2f(v0.x); a1 += bf2f(v0.y); a2 += bf2f(v0.z); a3 += bf2f(v0.w);
    }
    a0 += __shfl_down(a0, 32);
    a1 += __shfl_down(a1, 32);
    a2 += __shfl_down(a2, 32);
    a3 += __shfl_down(a3, 32);
    if (lane < 32) {
        float inv = 1.0f / fmaxf((float)dg, 1.0f);
        float m0 = a0 * inv, m1 = a1 * inv, m2 = a2 * inv, m3 = a3 * inv;
        ushort4 hi, lo;
        hi.x = f2bf(m0); hi.y = f2bf(m1); hi.z = f2bf(m2); hi.w = f2bf(m3);
        lo.x = f2bf(m0 - bf2f(hi.x)); lo.y = f2bf(m1 - bf2f(hi.y));
        lo.z = f2bf(m2 - bf2f(hi.z)); lo.w = f2bf(m3 - bf2f(hi.w));
        ((ushort4*)(aggh + (size_t)node * IN_F))[l32] = hi;
        ((ushort4*)(aggl + (size_t)node * IN_F))[l32] = lo;
    }
}

// ===================== fused layer1 (split-bf16 MFMA) + layer2 projections =====
__global__ __launch_bounds__(256, 2) void layer1_kernel(
        const unsigned short* __restrict__ xh, const unsigned short* __restrict__ xl,
        const unsigned short* __restrict__ aggh, const unsigned short* __restrict__ aggl,
        const unsigned short* __restrict__ Wh, const unsigned short* __restrict__ Wl,
        const float* __restrict__ b1l,
        const float* __restrict__ W2l, const float* __restrict__ W2r,
        float* __restrict__ p, float* __restrict__ q, int n) {
    __shared__ unsigned short Ah[128 * 32];   // [node][k] rows of 32 bf16 (64 B)
    __shared__ unsigned short Al[128 * 32];
    __shared__ unsigned short Bh[256 * 32];   // [feat][k]
    __shared__ unsigned short Bl[256 * 32];

    int tid  = threadIdx.x;
    int lane = tid & 63;
    int wv   = tid >> 6;
    int m15  = lane & 15;
    int quad = lane >> 4;
    int node0 = blockIdx.x * 128;

    f32x4 acc[2][16];
#pragma unroll
    for (int nt = 0; nt < 2; nt++)
#pragma unroll
        for (int ft = 0; ft < 16; ft++) acc[nt][ft] = (f32x4){0.f, 0.f, 0.f, 0.f};

    int rown = tid >> 2;   // 0..63
    int sub  = tid & 3;

    for (int kc = 0; kc < 8; kc++) {
        int k0 = kc * 32;
        const unsigned short* Ahs = (kc < 4) ? aggh : xh;
        const unsigned short* Als = (kc < 4) ? aggl : xl;
        int aoff = (kc < 4) ? k0 : (k0 - IN_F);

#pragma unroll
        for (int ps = 0; ps < 2; ps++) {
            int nl = ps * 64 + rown;
            int g  = node0 + nl;
            u16x8 hv = {0,0,0,0,0,0,0,0}, lv = {0,0,0,0,0,0,0,0};
            if (g < n) {
                size_t go = (size_t)g * IN_F + aoff + sub * 8;
                hv = *(const u16x8*)(Ahs + go);
                lv = *(const u16x8*)(Als + go);
            }
            *(u16x8*)&Ah[nl * 32 + sub * 8] = hv;
            *(u16x8*)&Al[nl * 32 + sub * 8] = lv;
        }
#pragma unroll
        for (int ps = 0; ps < 4; ps++) {
            int feat = ps * 64 + rown;
            size_t go = (size_t)feat * 256 + k0 + sub * 8;
            *(u16x8*)&Bh[feat * 32 + sub * 8] = *(const u16x8*)(Wh + go);
            *(u16x8*)&Bl[feat * 32 + sub * 8] = *(const u16x8*)(Wl + go);
        }
        __syncthreads();

        bf16x8 a0h = *(const bf16x8*)&Ah[(wv * 32 + m15) * 32 + quad * 8];
        bf16x8 a0l = *(const bf16x8*)&Al[(wv * 32 + m15) * 32 + quad * 8];
        bf16x8 a1h = *(const bf16x8*)&Ah[(wv * 32 + 16 + m15) * 32 + quad * 8];
        bf16x8 a1l = *(const bf16x8*)&Al[(wv * 32 + 16 + m15) * 32 + quad * 8];
#pragma unroll
        for (int ft = 0; ft < 16; ft++) {
            bf16x8 bh = *(const bf16x8*)&Bh[(ft * 16 + m15) * 32 + quad * 8];
            bf16x8 bl = *(const bf16x8*)&Bl[(ft * 16 + m15) * 32 + quad * 8];
            acc[0][ft] = __builtin_amdgcn_mfma_f32_16x16x32_bf16(a0h, bh, acc[0][ft], 0, 0, 0);
            acc[0][ft] = __builtin_amdgcn_mfma_f32_16x16x32_bf16(a0l, bh, acc[0][ft], 0, 0, 0);
            acc[0][ft] = __builtin_amdgcn_mfma_f32_16x16x32_bf16(a0h, bl, acc[0][ft], 0, 0, 0);
            acc[1][ft] = __builtin_amdgcn_mfma_f32_16x16x32_bf16(a1h, bh, acc[1][ft], 0, 0, 0);
            acc[1][ft] = __builtin_amdgcn_mfma_f32_16x16x32_bf16(a1l, bh, acc[1][ft], 0, 0, 0);
            acc[1][ft] = __builtin_amdgcn_mfma_f32_16x16x32_bf16(a1h, bl, acc[1][ft], 0, 0, 0);
        }
        __syncthreads();
    }

    // C/D layout: col(feat-in-tile)=lane&15, row(node-in-tile)=quad*4+reg
#pragma unroll
    for (int nt = 0; nt < 2; nt++) {
        float u0 = 0, u1 = 0, u2 = 0, u3 = 0;
        float v0 = 0, v1 = 0, v2 = 0, v3 = 0;
#pragma unroll
        for (int ft = 0; ft < 16; ft++) {
            int fj = ft * 16 + m15;
            float bb = b1l[fj], wl = W2l[fj], wr = W2r[fj];
            f32x4 c = acc[nt][ft];
            float h0 = fmaxf(c[0] + bb, 0.f);
            float h1 = fmaxf(c[1] + bb, 0.f);
            float h2 = fmaxf(c[2] + bb, 0.f);
            float h3 = fmaxf(c[3] + bb, 0.f);
            u0 += h0 * wl; v0 += h0 * wr;
            u1 += h1 * wl; v1 += h1 * wr;
            u2 += h2 * wl; v2 += h2 * wr;
            u3 += h3 * wl; v3 += h3 * wr;
        }
#pragma unroll
        for (int off = 1; off < 16; off <<= 1) {
            u0 += __shfl_xor(u0, off); v0 += __shfl_xor(v0, off);
            u1 += __shfl_xor(u1, off); v1 += __shfl_xor(v1, off);
            u2 += __shfl_xor(u2, off); v2 += __shfl_xor(v2, off);
            u3 += __shfl_xor(u3, off); v3 += __shfl_xor(v3, off);
        }
        if (m15 == 0) {
            int nb = node0 + wv * 32 + nt * 16 + quad * 4;
            if (nb + 0 < n) { p[nb + 0] = u0; q[nb + 0] = v0; }
            if (nb + 1 < n) { p[nb + 1] = u1; q[nb + 1] = v1; }
            if (nb + 2 < n) { p[nb + 2] = u2; q[nb + 2] = v2; }
            if (nb + 3 < n) { p[nb + 3] = u3; q[nb + 3] = v3; }
        }
    }
}

// ===================== final: out = mean(p[neigh]) + b2 + q; 16 lanes/node =====
__global__ void out_kernel(const float* __restrict__ p, const float* __restrict__ q,
                           const int* __restrict__ rowbeg, const int* __restrict__ degn,
                           const int* __restrict__ col,
                           const float* __restrict__ b2l,
                           float* __restrict__ out, int n) {
    int gid  = blockIdx.x * blockDim.x + threadIdx.x;
    int node = gid >> 4;
    int l    = threadIdx.x & 15;
    if (node >= n) return;
    int beg = rowbeg[node], dg = degn[node], end = beg + dg;
    float s = 0.f;
    for (int j = beg + l; j < end; j += 16) s += p[col[j]];
#pragma unroll
    for (int off = 8; off; off >>= 1) s += __shfl_xor(s, off);
    if (l == 0) {
        float inv = 1.0f / fmaxf((float)dg, 1.0f);
        out[node] = s * inv + b2l[0] + q[node];
    }
}

extern "C" void kernel_launch(void* const* d_in, const int* in_sizes, int n_in,
                              void* d_out, int out_size, void* d_ws, size_t ws_size,
                              hipStream_t stream) {
    const float* x   = (const float*)d_in[0];
    const int*   ei  = (const int*)  d_in[1];
    const float* W1l = (const float*)d_in[2];
    const float* b1l = (const float*)d_in[3];
    const float* W1r = (const float*)d_in[4];
    const float* W2l = (const float*)d_in[5];
    const float* b2l = (const float*)d_in[6];
    const float* W2r = (const float*)d_in[7];
    float* out = (float*)d_out;

    int n = in_sizes[0] / IN_F;   // 50000 (< 65536 required by edge packing)
    int E = in_sizes[1] / 2;      // 800000
    const int* src = ei;
    const int* dst = ei + E;

    size_t n_pad = ((size_t)n + 256) & ~(size_t)255;
    int nbk  = (n + 255) >> 8;            // 196 buckets
    int nblk = (E + ECH - 1) / ECH;       // 196 edge chunks

    int* ovf_cnt   = (int*)d_ws;                                   // 64 (aligned)
    unsigned* ovf  = (unsigned*)(ovf_cnt + 64);                    // OVF_CAP
    int* rcnt      = (int*)(ovf + OVF_CAP);                        // nblk*256 (<=65536)
    int* rowbeg    = rcnt + 65536;                                 // n_pad
    int* degn      = rowbeg + n_pad;                               // n_pad
    unsigned* btmp = (unsigned*)(degn + n_pad);                    // nblk*256*RSLOT
    int* col       = (int*)(btmp + (size_t)nblk * 256 * RSLOT);    // nbk*CAPB
    unsigned short* Whs = (unsigned short*)(col + (size_t)nbk * CAPB + 192);
    unsigned short* Wls  = Whs + 65536;
    unsigned short* xh   = Wls + 65536;                 // n*128 each
    unsigned short* xl   = xh + (size_t)n * IN_F;
    unsigned short* aggh = xl + (size_t)n * IN_F;
    unsigned short* aggl = aggh + (size_t)n * IN_F;
    float* p = (float*)(aggl + (size_t)n * IN_F);
    float* q = p + n_pad;

    hipMemsetAsync(ovf_cnt, 0, sizeof(int), stream);

    edge_bin<<<nblk, 256, 0, stream>>>(src, dst, btmp, rcnt, ovf_cnt, ovf, E);
    bucket_csr<<<nbk, 256, 0, stream>>>(btmp, rcnt, ovf_cnt, ovf,
                                        rowbeg, degn, col, n, nblk);

    long long total2 = (long long)n * IN_F / 2;
    long long tot = total2 + 65536;
    split_xw<<<(int)((tot + 255) / 256), 256, 0, stream>>>(
        x, W1l, W1r, xh, xl, Whs, Wls, total2);

    agg1_kernel<<<(int)(((size_t)n * 64 + 255) / 256), 256, 0, stream>>>(
        xh, rowbeg, degn, col, aggh, aggl, n);

    layer1_kernel<<<(n + 127) / 128, 256, 0, stream>>>(
        xh, xl, aggh, aggl, Whs, Wls, b1l, W2l, W2r, p, q, n);

    out_kernel<<<(int)(((size_t)n * 16 + 255) / 256), 256, 0, stream>>>(
        p, q, rowbeg, degn, col, b2l, out, n);
}

// Round 8
// 167.141 us; speedup vs baseline: 23.0670x; 1.1272x over previous
//
#include <hip/hip_runtime.h>

static constexpr int IN_F   = 128;
static constexpr int ECH    = 4096;   // edges per edge_bin block
static constexpr int RSLOT  = 64;     // btmp slots per (chunk,bucket); mean 20.9, +9sigma safe
static constexpr int CAPB   = 5376;   // col capacity per bucket (mean 4096, +20sigma)
static constexpr int CSR_CAP = 5376;
static constexpr int OVF_CAP = 4096;

typedef __attribute__((ext_vector_type(8))) short bf16x8;
typedef __attribute__((ext_vector_type(8))) unsigned short u16x8;
typedef __attribute__((ext_vector_type(4))) float f32x4;

__device__ inline unsigned short f2bf(float f) {   // RNE f32->bf16
    unsigned u = __float_as_uint(f);
    u += 0x7FFF + ((u >> 16) & 1);
    return (unsigned short)(u >> 16);
}
__device__ inline float bf2f(unsigned short h) {
    return __uint_as_float(((unsigned)h) << 16);
}

// ===================== CSR stage 1: bin edges into static (chunk,bucket) slots ====
__global__ __launch_bounds__(256) void edge_bin(const int* __restrict__ src,
        const int* __restrict__ dst, unsigned* __restrict__ btmp,
        int* __restrict__ rcnt, int* __restrict__ ovf_cnt, unsigned* __restrict__ ovf,
        int E) {
    __shared__ unsigned stage[ECH];
    __shared__ int h[256], lcur[256];
    int tid = threadIdx.x, eb = blockIdx.x;
    int base = eb * ECH;
    h[tid] = 0; lcur[tid] = 0;
    __syncthreads();
#pragma unroll
    for (int r = 0; r < ECH / 256; r++) {
        int e = base + r * 256 + tid;
        if (e < E) {
            unsigned d = (unsigned)dst[e];
            stage[r * 256 + tid] = (d << 16) | (unsigned)src[e];
            atomicAdd(&h[d >> 8], 1);
        }
    }
    __syncthreads();
    int hv = h[tid];
    rcnt[eb * 256 + tid] = hv < RSLOT ? hv : RSLOT;
#pragma unroll
    for (int r = 0; r < ECH / 256; r++) {
        int e = base + r * 256 + tid;
        if (e < E) {
            unsigned pk = stage[r * 256 + tid];
            int bkt = pk >> 24;
            int rank = atomicAdd(&lcur[bkt], 1);
            if (rank < RSLOT)
                btmp[(size_t)(eb * 256 + bkt) * RSLOT + rank] = pk;
            else {
                int pos = atomicAdd(ovf_cnt, 1);
                if (pos < OVF_CAP) ovf[pos] = pk;
            }
        }
    }
}

// ===================== CSR stage 2: per-bucket compact + local CSR =====================
__global__ __launch_bounds__(256) void bucket_csr(const unsigned* __restrict__ btmp,
        const int* __restrict__ rcnt, const int* __restrict__ ovf_cnt,
        const unsigned* __restrict__ ovf,
        int* __restrict__ rowbeg, int* __restrict__ degn, int* __restrict__ col,
        int n, int nblk) {
    __shared__ unsigned stage[CSR_CAP];
    __shared__ unsigned colL[CSR_CAP];
    __shared__ int cntL[256], curL[256];
    __shared__ int ws[4];
    __shared__ int s_extra;
    int b = blockIdx.x, tid = threadIdx.x, lane = tid & 63, wid = tid >> 6;

    int rc = (tid < nblk) ? rcnt[tid * 256 + b] : 0;
    int val = rc;
#pragma unroll
    for (int off = 1; off < 64; off <<= 1) {
        int t = __shfl_up(val, off);
        if (lane >= off) val += t;
    }
    if (lane == 63) ws[wid] = val;
    if (tid == 0) s_extra = 0;
    cntL[tid] = 0;
    __syncthreads();
    int pre = 0;
    for (int w = 0; w < wid; w++) pre += ws[w];
    int rb  = pre + val - rc;
    int cnt = ws[0] + ws[1] + ws[2] + ws[3];
    if (tid < nblk && rc > 0) {
        const unsigned* sp = btmp + (size_t)(tid * 256 + b) * RSLOT;
        for (int i = 0; i < rc; i++) stage[rb + i] = sp[i];
    }
    __syncthreads();
    int novf = *ovf_cnt;
    if (novf > 0) {
        if (novf > OVF_CAP) novf = OVF_CAP;
        for (int i = tid; i < novf; i += 256) {
            unsigned pk = ovf[i];
            if ((int)(pk >> 24) == b) {
                int pos = atomicAdd(&s_extra, 1);
                if (cnt + pos < CSR_CAP) stage[cnt + pos] = pk;
            }
        }
    }
    __syncthreads();
    cnt += s_extra;
    if (cnt > CSR_CAP) cnt = CSR_CAP;
    for (int i = tid; i < cnt; i += 256) atomicAdd(&cntL[(stage[i] >> 16) & 255], 1);
    __syncthreads();
    int v = cntL[tid];
    int val2 = v;
#pragma unroll
    for (int off = 1; off < 64; off <<= 1) {
        int t = __shfl_up(val2, off);
        if (lane >= off) val2 += t;
    }
    if (lane == 63) ws[wid] = val2;
    __syncthreads();
    pre = 0;
    for (int w = 0; w < wid; w++) pre += ws[w];
    int ex = pre + val2 - v;
    curL[tid] = ex;
    int node = b * 256 + tid;
    if (node < n) { rowbeg[node] = b * CAPB + ex; degn[node] = v; }
    __syncthreads();
    for (int i = tid; i < cnt; i += 256) {
        unsigned pk = stage[i];
        int pos = atomicAdd(&curL[(pk >> 16) & 255], 1);
        colL[pos] = pk & 0xFFFFu;
    }
    __syncthreads();
    for (int i = tid; i < cnt; i += 256) col[b * CAPB + i] = (int)colL[i];
}

// ===================== fused split of x (bf16) and W (hi/lo, k-major concat) =====
__global__ __launch_bounds__(256) void split_xw(const float* __restrict__ x,
        const float* __restrict__ W1l, const float* __restrict__ W1r,
        unsigned short* __restrict__ xh,
        unsigned short* __restrict__ Wh, unsigned short* __restrict__ Wl,
        long long total2) {
    long long i = (long long)blockIdx.x * 256 + threadIdx.x;
    if (i < total2) {
        float2 v = ((const float2*)x)[i];
        ((ushort2*)xh)[i] = make_ushort2(f2bf(v.x), f2bf(v.y));
    } else {
        long long wi = i - total2;
        if (wi < 65536) {
            int feat = (int)(wi >> 8), k = (int)(wi & 255);
            float w = (k < IN_F) ? W1l[feat * IN_F + k] : W1r[feat * IN_F + (k - IN_F)];
            unsigned short h = f2bf(w);
            Wh[wi] = h;
            Wl[wi] = f2bf(w - bf2f(h));
        }
    }
}

// ===================== agg1: mean of x_hi rows; 32 lanes/node, 4 rows in flight ====
__global__ void agg1_kernel(const unsigned short* __restrict__ xh,
                            const int* __restrict__ rowbeg, const int* __restrict__ degn,
                            const int* __restrict__ col,
                            unsigned short* __restrict__ aggh, int n) {
    int gid  = blockIdx.x * blockDim.x + threadIdx.x;
    int node = gid >> 5;               // 32 lanes per node
    int l32  = threadIdx.x & 31;
    if (node >= n) return;
    int beg = rowbeg[node], dg = degn[node], end = beg + dg;
    float a0 = 0.f, a1 = 0.f, a2 = 0.f, a3 = 0.f;
    int j = beg;
    for (; j + 3 < end; j += 4) {
        int4 cs = *(const int4*)(col + j);          // 4 indices, one 16B load
        ushort4 v0 = ((const ushort4*)(xh + (size_t)cs.x * IN_F))[l32];
        ushort4 v1 = ((const ushort4*)(xh + (size_t)cs.y * IN_F))[l32];
        ushort4 v2 = ((const ushort4*)(xh + (size_t)cs.z * IN_F))[l32];
        ushort4 v3 = ((const ushort4*)(xh + (size_t)cs.w * IN_F))[l32];
        a0 += bf2f(v0.x) + bf2f(v1.x) + bf2f(v2.x) + bf2f(v3.x);
        a1 += bf2f(v0.y) + bf2f(v1.y) + bf2f(v2.y) + bf2f(v3.y);
        a2 += bf2f(v0.z) + bf2f(v1.z) + bf2f(v2.z) + bf2f(v3.z);
        a3 += bf2f(v0.w) + bf2f(v1.w) + bf2f(v2.w) + bf2f(v3.w);
    }
    for (; j < end; j++) {
        ushort4 v0 = ((const ushort4*)(xh + (size_t)col[j] * IN_F))[l32];
        a0 += bf2f(v0.x); a1 += bf2f(v0.y); a2 += bf2f(v0.z); a3 += bf2f(v0.w);
    }
    float inv = 1.0f / fmaxf((float)dg, 1.0f);
    ushort4 hi;
    hi.x = f2bf(a0 * inv); hi.y = f2bf(a1 * inv);
    hi.z = f2bf(a2 * inv); hi.w = f2bf(a3 * inv);
    ((ushort4*)(aggh + (size_t)node * IN_F))[l32] = hi;
}

// ===================== fused layer1 (bf16 A, split-bf16 W) + layer2 projections ====
// C = [agg|x] @ [W1l|W1r]^T via Ah*(Wh+Wl); h = relu(C+b1); p=h.W2l q=h.W2r.
__global__ __launch_bounds__(256, 2) void layer1_kernel(
        const unsigned short* __restrict__ xh,
        const unsigned short* __restrict__ aggh,
        const unsigned short* __restrict__ Wh, const unsigned short* __restrict__ Wl,
        const float* __restrict__ b1l,
        const float* __restrict__ W2l, const float* __restrict__ W2r,
        float* __restrict__ p, float* __restrict__ q, int n) {
    __shared__ unsigned short Ah[128 * 32];   // [node][k] rows of 32 bf16 (64 B)
    __shared__ unsigned short Bh[256 * 32];   // [feat][k]
    __shared__ unsigned short Bl[256 * 32];

    int tid  = threadIdx.x;
    int lane = tid & 63;
    int wv   = tid >> 6;
    int m15  = lane & 15;
    int quad = lane >> 4;
    int node0 = blockIdx.x * 128;

    f32x4 acc[2][16];
#pragma unroll
    for (int nt = 0; nt < 2; nt++)
#pragma unroll
        for (int ft = 0; ft < 16; ft++) acc[nt][ft] = (f32x4){0.f, 0.f, 0.f, 0.f};

    int rown = tid >> 2;   // 0..63
    int sub  = tid & 3;

    for (int kc = 0; kc < 8; kc++) {
        int k0 = kc * 32;
        const unsigned short* Ahs = (kc < 4) ? aggh : xh;
        int aoff = (kc < 4) ? k0 : (k0 - IN_F);

#pragma unroll
        for (int ps = 0; ps < 2; ps++) {
            int nl = ps * 64 + rown;
            int g  = node0 + nl;
            u16x8 hv = {0,0,0,0,0,0,0,0};
            if (g < n) hv = *(const u16x8*)(Ahs + (size_t)g * IN_F + aoff + sub * 8);
            *(u16x8*)&Ah[nl * 32 + sub * 8] = hv;
        }
#pragma unroll
        for (int ps = 0; ps < 4; ps++) {
            int feat = ps * 64 + rown;
            size_t go = (size_t)feat * 256 + k0 + sub * 8;
            *(u16x8*)&Bh[feat * 32 + sub * 8] = *(const u16x8*)(Wh + go);
            *(u16x8*)&Bl[feat * 32 + sub * 8] = *(const u16x8*)(Wl + go);
        }
        __syncthreads();

        bf16x8 a0h = *(const bf16x8*)&Ah[(wv * 32 + m15) * 32 + quad * 8];
        bf16x8 a1h = *(const bf16x8*)&Ah[(wv * 32 + 16 + m15) * 32 + quad * 8];
#pragma unroll
        for (int ft = 0; ft < 16; ft++) {
            bf16x8 bh = *(const bf16x8*)&Bh[(ft * 16 + m15) * 32 + quad * 8];
            bf16x8 bl = *(const bf16x8*)&Bl[(ft * 16 + m15) * 32 + quad * 8];
            acc[0][ft] = __builtin_amdgcn_mfma_f32_16x16x32_bf16(a0h, bh, acc[0][ft], 0, 0, 0);
            acc[0][ft] = __builtin_amdgcn_mfma_f32_16x16x32_bf16(a0h, bl, acc[0][ft], 0, 0, 0);
            acc[1][ft] = __builtin_amdgcn_mfma_f32_16x16x32_bf16(a1h, bh, acc[1][ft], 0, 0, 0);
            acc[1][ft] = __builtin_amdgcn_mfma_f32_16x16x32_bf16(a1h, bl, acc[1][ft], 0, 0, 0);
        }
        __syncthreads();
    }

    // C/D layout: col(feat-in-tile)=lane&15, row(node-in-tile)=quad*4+reg
#pragma unroll
    for (int nt = 0; nt < 2; nt++) {
        float u0 = 0, u1 = 0, u2 = 0, u3 = 0;
        float v0 = 0, v1 = 0, v2 = 0, v3 = 0;
#pragma unroll
        for (int ft = 0; ft < 16; ft++) {
            int fj = ft * 16 + m15;
            float bb = b1l[fj], wl = W2l[fj], wr = W2r[fj];
            f32x4 c = acc[nt][ft];
            float h0 = fmaxf(c[0] + bb, 0.f);
            float h1 = fmaxf(c[1] + bb, 0.f);
            float h2 = fmaxf(c[2] + bb, 0.f);
            float h3 = fmaxf(c[3] + bb, 0.f);
            u0 += h0 * wl; v0 += h0 * wr;
            u1 += h1 * wl; v1 += h1 * wr;
            u2 += h2 * wl; v2 += h2 * wr;
            u3 += h3 * wl; v3 += h3 * wr;
        }
#pragma unroll
        for (int off = 1; off < 16; off <<= 1) {
            u0 += __shfl_xor(u0, off); v0 += __shfl_xor(v0, off);
            u1 += __shfl_xor(u1, off); v1 += __shfl_xor(v1, off);
            u2 += __shfl_xor(u2, off); v2 += __shfl_xor(v2, off);
            u3 += __shfl_xor(u3, off); v3 += __shfl_xor(v3, off);
        }
        if (m15 == 0) {
            int nb = node0 + wv * 32 + nt * 16 + quad * 4;
            if (nb + 0 < n) { p[nb + 0] = u0; q[nb + 0] = v0; }
            if (nb + 1 < n) { p[nb + 1] = u1; q[nb + 1] = v1; }
            if (nb + 2 < n) { p[nb + 2] = u2; q[nb + 2] = v2; }
            if (nb + 3 < n) { p[nb + 3] = u3; q[nb + 3] = v3; }
        }
    }
}

// ===================== final: out = mean(p[neigh]) + b2 + q; 16 lanes/node =====
__global__ void out_kernel(const float* __restrict__ p, const float* __restrict__ q,
                           const int* __restrict__ rowbeg, const int* __restrict__ degn,
                           const int* __restrict__ col,
                           const float* __restrict__ b2l,
                           float* __restrict__ out, int n) {
    int gid  = blockIdx.x * blockDim.x + threadIdx.x;
    int node = gid >> 4;
    int l    = threadIdx.x & 15;
    if (node >= n) return;
    int beg = rowbeg[node], dg = degn[node], end = beg + dg;
    float s = 0.f;
    for (int j = beg + l; j < end; j += 16) s += p[col[j]];
#pragma unroll
    for (int off = 8; off; off >>= 1) s += __shfl_xor(s, off);
    if (l == 0) {
        float inv = 1.0f / fmaxf((float)dg, 1.0f);
        out[node] = s * inv + b2l[0] + q[node];
    }
}

extern "C" void kernel_launch(void* const* d_in, const int* in_sizes, int n_in,
                              void* d_out, int out_size, void* d_ws, size_t ws_size,
                              hipStream_t stream) {
    const float* x   = (const float*)d_in[0];
    const int*   ei  = (const int*)  d_in[1];
    const float* W1l = (const float*)d_in[2];
    const float* b1l = (const float*)d_in[3];
    const float* W1r = (const float*)d_in[4];
    const float* W2l = (const float*)d_in[5];
    const float* b2l = (const float*)d_in[6];
    const float* W2r = (const float*)d_in[7];
    float* out = (float*)d_out;

    int n = in_sizes[0] / IN_F;   // 50000 (< 65536 required by edge packing)
    int E = in_sizes[1] / 2;      // 800000
    const int* src = ei;
    const int* dst = ei + E;

    size_t n_pad = ((size_t)n + 256) & ~(size_t)255;
    int nbk  = (n + 255) >> 8;            // 196 buckets
    int nblk = (E + ECH - 1) / ECH;       // 196 edge chunks

    int* ovf_cnt   = (int*)d_ws;                                   // 64 (aligned)
    unsigned* ovf  = (unsigned*)(ovf_cnt + 64);                    // OVF_CAP
    int* rcnt      = (int*)(ovf + OVF_CAP);                        // nblk*256 (<=65536)
    int* rowbeg    = rcnt + 65536;                                 // n_pad
    int* degn      = rowbeg + n_pad;                               // n_pad
    unsigned* btmp = (unsigned*)(degn + n_pad);                    // nblk*256*RSLOT
    int* col       = (int*)(btmp + (size_t)nblk * 256 * RSLOT);    // nbk*CAPB
    unsigned short* Whs = (unsigned short*)(col + (size_t)nbk * CAPB + 192);
    unsigned short* Wls  = Whs + 65536;
    unsigned short* xh   = Wls + 65536;                 // n*128
    unsigned short* aggh = xh + (size_t)n * IN_F;       // n*128
    float* p = (float*)(aggh + (size_t)n * IN_F);
    float* q = p + n_pad;

    hipMemsetAsync(ovf_cnt, 0, sizeof(int), stream);

    edge_bin<<<nblk, 256, 0, stream>>>(src, dst, btmp, rcnt, ovf_cnt, ovf, E);
    bucket_csr<<<nbk, 256, 0, stream>>>(btmp, rcnt, ovf_cnt, ovf,
                                        rowbeg, degn, col, n, nblk);

    long long total2 = (long long)n * IN_F / 2;
    long long tot = total2 + 65536;
    split_xw<<<(int)((tot + 255) / 256), 256, 0, stream>>>(
        x, W1l, W1r, xh, Whs, Wls, total2);

    agg1_kernel<<<(int)(((size_t)n * 32 + 255) / 256), 256, 0, stream>>>(
        xh, rowbeg, degn, col, aggh, n);

    layer1_kernel<<<(n + 127) / 128, 256, 0, stream>>>(
        xh, aggh, Whs, Wls, b1l, W2l, W2r, p, q, n);

    out_kernel<<<(int)(((size_t)n * 16 + 255) / 256), 256, 0, stream>>>(
        p, q, rowbeg, degn, col, b2l, out, n);
}